// Round 1
// baseline (831.697 us; speedup 1.0000x reference)
//
#include <hip/hip_runtime.h>
#include <math.h>

// Problem constants (from reference)
#define NNODES 100000
#define NREL 500
#define E1 288000
#define ETOT 320000
#define LALPHA 0.2f
#define SEPS 1e-16f
#define NB_SCAN ((NNODES + 255) / 256)  // 391 blocks of 256 for the scan

// ---------------- wave (64-lane) reductions ----------------
__device__ __forceinline__ float wave_max64(float v) {
#pragma unroll
  for (int o = 32; o >= 1; o >>= 1) v = fmaxf(v, __shfl_xor(v, o, 64));
  return v;
}
__device__ __forceinline__ float wave_sum64(float v) {
#pragma unroll
  for (int o = 32; o >= 1; o >>= 1) v += __shfl_xor(v, o, 64);
  return v;
}

// ---------------- CSR build ----------------
__global__ void k_zero_int(int* __restrict__ p, int n) {
  int i = blockIdx.x * blockDim.x + threadIdx.x;
  if (i < n) p[i] = 0;
}

__global__ void k_count(const int* __restrict__ src, int* __restrict__ cnt) {
  int e = blockIdx.x * blockDim.x + threadIdx.x;
  if (e < ETOT) atomicAdd(&cnt[src[e]], 1);
}

__global__ void k_scan_a(const int* __restrict__ cnt, int* __restrict__ rowstart,
                         int* __restrict__ blockTot) {
  __shared__ int s[256];
  int t = threadIdx.x;
  int idx = blockIdx.x * 256 + t;
  int v = (idx < NNODES) ? cnt[idx] : 0;
  s[t] = v;
  __syncthreads();
  for (int off = 1; off < 256; off <<= 1) {
    int xv = (t >= off) ? s[t - off] : 0;
    __syncthreads();
    s[t] += xv;
    __syncthreads();
  }
  if (idx < NNODES) rowstart[idx] = s[t] - v;  // exclusive within block
  if (t == 255) blockTot[blockIdx.x] = s[255];
}

__global__ void k_scan_b(const int* __restrict__ blockTot, int* __restrict__ blockOff) {
  __shared__ int s[512];
  int t = threadIdx.x;
  int v = (t < NB_SCAN) ? blockTot[t] : 0;
  s[t] = v;
  __syncthreads();
  for (int off = 1; off < 512; off <<= 1) {
    int xv = (t >= off) ? s[t - off] : 0;
    __syncthreads();
    s[t] += xv;
    __syncthreads();
  }
  if (t < NB_SCAN) blockOff[t] = s[t] - v;  // exclusive
}

__global__ void k_scan_c(int* __restrict__ rowstart, const int* __restrict__ blockOff,
                         int* __restrict__ cursor) {
  int idx = blockIdx.x * 256 + threadIdx.x;
  if (idx < NNODES) {
    int v = rowstart[idx] + blockOff[blockIdx.x];
    rowstart[idx] = v;
    cursor[idx] = v;
  }
  if (idx == 0) rowstart[NNODES] = ETOT;
}

__global__ void k_scatter(const int* __restrict__ src, int* __restrict__ cursor,
                          int* __restrict__ perm) {
  int e = blockIdx.x * blockDim.x + threadIdx.x;
  if (e < ETOT) {
    int pos = atomicAdd(&cursor[src[e]], 1);
    perm[pos] = e;
  }
}

// ---------------- relation-level precompute ----------------
// rW1[h][t][k] = sum_d r[t][d] * W_heads[h][256+d][k]; srel1[h][t] = rW1 . a_heads[h]
__global__ void k_relprep1(const float* __restrict__ r, const float* __restrict__ Wh,
                           const float* __restrict__ ah, float* __restrict__ rW1,
                           float* __restrict__ srel1) {
  int b = blockIdx.x;           // 0..999
  int h = b / NREL;             // 0..1
  int t = b - h * NREL;         // 0..499
  int k = threadIdx.x;          // 0..63
  const float* wcol = Wh + h * 384 * 64 + 256 * 64 + k;
  const float* rrow = r + t * 128;
  float acc = 0.f;
#pragma unroll 4
  for (int d = 0; d < 128; ++d) acc = fmaf(rrow[d], wcol[d * 64], acc);
  rW1[(h * NREL + t) * 64 + k] = acc;
  float p = wave_sum64(acc * ah[h * 64 + k]);
  if (k == 0) srel1[h * NREL + t] = p;
}

// r2[t][c] = sum_d r[t][d] * W_r[d][c]   (also one of the two outputs)
__global__ void k_r2(const float* __restrict__ r, const float* __restrict__ Wr,
                     float* __restrict__ r2out) {
  int t = blockIdx.x;   // 0..499
  int c = threadIdx.x;  // 0..127
  float acc = 0.f;
#pragma unroll 4
  for (int d = 0; d < 128; ++d) acc = fmaf(r[t * 128 + d], Wr[d * 128 + c], acc);
  r2out[t * 128 + c] = acc;
}

// rW2[t][k] = sum_d r2[t][d] * W_out[256+d][k]; srel2[t] = rW2 . a_out
__global__ void k_relprep2(const float* __restrict__ r2, const float* __restrict__ Wo,
                           const float* __restrict__ ao, float* __restrict__ rW2,
                           float* __restrict__ srel2) {
  __shared__ float s[128];
  int t = blockIdx.x;   // 0..499
  int k = threadIdx.x;  // 0..127
  float acc = 0.f;
#pragma unroll 4
  for (int d = 0; d < 128; ++d) acc = fmaf(r2[t * 128 + d], Wo[(256 + d) * 128 + k], acc);
  rW2[t * 128 + k] = acc;
  s[k] = acc * ao[k];
  __syncthreads();
  for (int off = 64; off >= 1; off >>= 1) {
    if (k < off) s[k] += s[k + off];
    __syncthreads();
  }
  if (k == 0) srel2[t] = s[0];
}

// ---------------- W packing (d-major for coalesced GEMM reads) ----------------
// Layer1 cols: c = h*128 + part*64 + k  (part 0 = src block, 1 = dst block)
__global__ void k_pack1(const float* __restrict__ Wh, float* __restrict__ Wp) {
  int d = blockIdx.x;   // 0..127
  int c = threadIdx.x;  // 0..255
  int h = c >> 7, part = (c >> 6) & 1, k = c & 63;
  Wp[d * 256 + c] = Wh[h * 24576 + (part * 128 + d) * 64 + k];
}
// Layer2 cols: c = part*128 + k
__global__ void k_pack2(const float* __restrict__ Wo, float* __restrict__ Wp) {
  int d = blockIdx.x;
  int c = threadIdx.x;
  int part = c >> 7, k = c & 127;
  Wp[d * 256 + c] = Wo[(part * 128 + d) * 128 + k];
}

// ---------------- node-level GEMM: Y[N][256] = X[N][128] @ Wp[128][256] ----------------
__global__ __launch_bounds__(256) void k_gemm(const float* __restrict__ X,
                                              const float* __restrict__ Wp,
                                              float* __restrict__ Y) {
  __shared__ float xs[32][128];
  const int t = threadIdx.x;
  const size_t nbase = (size_t)blockIdx.x * 32;  // 100000 = 32*3125, exact
  const float4* Xv = (const float4*)(X + nbase * 128);
  float4* sv = (float4*)(&xs[0][0]);
#pragma unroll
  for (int i = 0; i < 4; ++i) sv[t + i * 256] = Xv[t + i * 256];
  __syncthreads();
  const int cg = t & 31, ng = t >> 5;
  const int c0 = cg * 8, n0 = ng * 4;
  float acc[4][8];
#pragma unroll
  for (int i = 0; i < 4; ++i)
#pragma unroll
    for (int j = 0; j < 8; ++j) acc[i][j] = 0.f;

  for (int d = 0; d < 128; d += 4) {
    float xv[4][4];
#pragma unroll
    for (int i = 0; i < 4; ++i) *(float4*)&xv[i][0] = *(const float4*)&xs[n0 + i][d];
#pragma unroll
    for (int dd = 0; dd < 4; ++dd) {
      float4 wa = *(const float4*)(Wp + (d + dd) * 256 + c0);
      float4 wb = *(const float4*)(Wp + (d + dd) * 256 + c0 + 4);
      float w[8] = {wa.x, wa.y, wa.z, wa.w, wb.x, wb.y, wb.z, wb.w};
#pragma unroll
      for (int i = 0; i < 4; ++i)
#pragma unroll
        for (int j = 0; j < 8; ++j) acc[i][j] = fmaf(xv[i][dd], w[j], acc[i][j]);
    }
  }
#pragma unroll
  for (int i = 0; i < 4; ++i) {
    float* yp = Y + (nbase + n0 + i) * 256 + c0;
    *(float4*)yp = make_float4(acc[i][0], acc[i][1], acc[i][2], acc[i][3]);
    *(float4*)(yp + 4) = make_float4(acc[i][4], acc[i][5], acc[i][6], acc[i][7]);
  }
}

// ---------------- per-node logit scalars ----------------
// sc1[n][4] = {ss_h0, sd_h0, ss_h1, sd_h1}
__global__ void k_scal1(const float* __restrict__ xW, const float* __restrict__ ah,
                        float* __restrict__ sc1) {
  int n = blockIdx.x * 4 + (threadIdx.x >> 6);
  int lane = threadIdx.x & 63;
  if (n >= NNODES) return;
  const float* row = xW + (size_t)n * 256;
  float a0 = ah[lane], a1 = ah[64 + lane];
  float v0 = wave_sum64(row[lane] * a0);
  float v1 = wave_sum64(row[64 + lane] * a0);
  float v2 = wave_sum64(row[128 + lane] * a1);
  float v3 = wave_sum64(row[192 + lane] * a1);
  if (lane == 0) {
    float* o = sc1 + (size_t)n * 4;
    o[0] = v0; o[1] = v1; o[2] = v2; o[3] = v3;
  }
}

// sc2[n][2] = {ss, sd}
__global__ void k_scal2(const float* __restrict__ xW, const float* __restrict__ ao,
                        float* __restrict__ sc2) {
  int n = blockIdx.x * 4 + (threadIdx.x >> 6);
  int lane = threadIdx.x & 63;
  if (n >= NNODES) return;
  const float* row = xW + (size_t)n * 256;
  float a0 = ao[lane], a1 = ao[64 + lane];
  float v0 = wave_sum64(row[lane] * a0 + row[64 + lane] * a1);
  float v1 = wave_sum64(row[128 + lane] * a0 + row[192 + lane] * a1);
  if (lane == 0) {
    sc2[(size_t)n * 2] = v0;
    sc2[(size_t)n * 2 + 1] = v1;
  }
}

// ---------------- per-edge relation scalar helpers ----------------
__device__ __forceinline__ float relscal1(int ed, int h, const int* __restrict__ et,
                                          const int* __restrict__ et2,
                                          const float* __restrict__ srel1) {
  if (ed < E1) return srel1[h * NREL + et[ed]];
  int j = ed - E1;
  return srel1[h * NREL + et2[2 * j]] + srel1[h * NREL + et2[2 * j + 1]];
}
__device__ __forceinline__ float relscal2(int ed, const int* __restrict__ et,
                                          const int* __restrict__ et2,
                                          const float* __restrict__ srel2) {
  if (ed < E1) return srel2[et[ed]];
  int j = ed - E1;
  return srel2[et2[2 * j]] + srel2[et2[2 * j + 1]];
}

__device__ __forceinline__ float logit1(int ed, int h, float ssn, const int* __restrict__ dstA,
                                        const int* __restrict__ et, const int* __restrict__ et2,
                                        const float* __restrict__ sc1,
                                        const float* __restrict__ srel1) {
  float e = ssn + sc1[(size_t)dstA[ed] * 4 + h * 2 + 1] + relscal1(ed, h, et, et2, srel1);
  return (e >= 0.f) ? e : LALPHA * e;
}
__device__ __forceinline__ float logit2(int ed, float ssn, const int* __restrict__ dstA,
                                        const int* __restrict__ et, const int* __restrict__ et2,
                                        const float* __restrict__ sc2,
                                        const float* __restrict__ srel2) {
  float e = ssn + sc2[(size_t)dstA[ed] * 2 + 1] + relscal2(ed, et, et2, srel2);
  return (e >= 0.f) ? e : LALPHA * e;
}

// ---------------- layer-1 aggregation: one wave per (node, head) ----------------
__global__ void k_agg1(const int* __restrict__ rowstart, const int* __restrict__ perm,
                       const int* __restrict__ dstA, const int* __restrict__ et,
                       const int* __restrict__ et2, const float* __restrict__ xW,
                       const float* __restrict__ sc1, const float* __restrict__ rW1,
                       const float* __restrict__ srel1, float* __restrict__ x1) {
  int wid = blockIdx.x * 4 + (threadIdx.x >> 6);
  int lane = threadIdx.x & 63;
  int n = wid >> 1, h = wid & 1;
  if (n >= NNODES) return;
  int s0 = rowstart[n];
  int deg = rowstart[n + 1] - s0;
  float out = 0.f;
  if (deg > 0) {
    float ssn = sc1[(size_t)n * 4 + h * 2];
    // pass 1: segment max of leaky logits
    float m = -3.4e38f;
    for (int base = 0; base < deg; base += 64) {
      int i = base + lane;
      float lg = -3.4e38f;
      if (i < deg) lg = logit1(perm[s0 + i], h, ssn, dstA, et, et2, sc1, srel1);
      m = fmaxf(m, lg);
    }
    m = wave_max64(m);
    // pass 2: denominator
    float dsum = 0.f;
    for (int base = 0; base < deg; base += 64) {
      int i = base + lane;
      if (i < deg) {
        float lg = logit1(perm[s0 + i], h, ssn, dstA, et, et2, sc1, srel1);
        dsum += __expf(lg - m);
      }
    }
    dsum = wave_sum64(dsum);
    float inv = 1.f / (dsum + SEPS);
    // pass 3: weighted accumulation (serial broadcast per edge)
    float acc = 0.f, sumatt = 0.f;
    for (int base = 0; base < deg; base += 64) {
      int i = base + lane;
      int ed = 0;
      float w = 0.f;
      if (i < deg) {
        ed = perm[s0 + i];
        w = __expf(logit1(ed, h, ssn, dstA, et, et2, sc1, srel1) - m) * inv;
      }
      int cntc = min(64, deg - base);
      for (int e2 = 0; e2 < cntc; ++e2) {
        float att = __shfl(w, e2, 64);
        int ede = __shfl(ed, e2, 64);
        float relv;
        if (ede < E1) {
          relv = rW1[((size_t)h * NREL + et[ede]) * 64 + lane];
        } else {
          int j = ede - E1;
          relv = rW1[((size_t)h * NREL + et2[2 * j]) * 64 + lane] +
                 rW1[((size_t)h * NREL + et2[2 * j + 1]) * 64 + lane];
        }
        int dn = dstA[ede];
        acc = fmaf(att, xW[(size_t)dn * 256 + h * 128 + 64 + lane] + relv, acc);
        sumatt += att;
      }
    }
    out = acc + sumatt * xW[(size_t)n * 256 + h * 128 + lane];
  }
  float res = (out > 0.f) ? out : (__expf(out) - 1.f);  // elu (concat=True)
  x1[(size_t)n * 128 + h * 64 + lane] = res;
}

// ---------------- layer-2 aggregation: one wave per node, 128 dims (lane, lane+64) ----------------
__global__ void k_agg2(const int* __restrict__ rowstart, const int* __restrict__ perm,
                       const int* __restrict__ dstA, const int* __restrict__ et,
                       const int* __restrict__ et2, const float* __restrict__ xW,
                       const float* __restrict__ sc2, const float* __restrict__ rW2,
                       const float* __restrict__ srel2, float* __restrict__ outp) {
  int n = blockIdx.x * 4 + (threadIdx.x >> 6);
  int lane = threadIdx.x & 63;
  if (n >= NNODES) return;
  int s0 = rowstart[n];
  int deg = rowstart[n + 1] - s0;
  float o0 = 0.f, o1 = 0.f;
  if (deg > 0) {
    float ssn = sc2[(size_t)n * 2];
    float m = -3.4e38f;
    for (int base = 0; base < deg; base += 64) {
      int i = base + lane;
      float lg = -3.4e38f;
      if (i < deg) lg = logit2(perm[s0 + i], ssn, dstA, et, et2, sc2, srel2);
      m = fmaxf(m, lg);
    }
    m = wave_max64(m);
    float dsum = 0.f;
    for (int base = 0; base < deg; base += 64) {
      int i = base + lane;
      if (i < deg) {
        float lg = logit2(perm[s0 + i], ssn, dstA, et, et2, sc2, srel2);
        dsum += __expf(lg - m);
      }
    }
    dsum = wave_sum64(dsum);
    float inv = 1.f / (dsum + SEPS);
    float acc0 = 0.f, acc1 = 0.f, sumatt = 0.f;
    for (int base = 0; base < deg; base += 64) {
      int i = base + lane;
      int ed = 0;
      float w = 0.f;
      if (i < deg) {
        ed = perm[s0 + i];
        w = __expf(logit2(ed, ssn, dstA, et, et2, sc2, srel2) - m) * inv;
      }
      int cntc = min(64, deg - base);
      for (int e2 = 0; e2 < cntc; ++e2) {
        float att = __shfl(w, e2, 64);
        int ede = __shfl(ed, e2, 64);
        float relv0, relv1;
        if (ede < E1) {
          const float* rr = rW2 + (size_t)et[ede] * 128;
          relv0 = rr[lane];
          relv1 = rr[64 + lane];
        } else {
          int j = ede - E1;
          const float* ra = rW2 + (size_t)et2[2 * j] * 128;
          const float* rb = rW2 + (size_t)et2[2 * j + 1] * 128;
          relv0 = ra[lane] + rb[lane];
          relv1 = ra[64 + lane] + rb[64 + lane];
        }
        int dn = dstA[ede];
        const float* dw = xW + (size_t)dn * 256 + 128;
        acc0 = fmaf(att, dw[lane] + relv0, acc0);
        acc1 = fmaf(att, dw[64 + lane] + relv1, acc1);
        sumatt += att;
      }
    }
    o0 = acc0 + sumatt * xW[(size_t)n * 256 + lane];
    o1 = acc1 + sumatt * xW[(size_t)n * 256 + 64 + lane];
  }
  // final elu (applied once on concat=False layer output)
  float r0 = (o0 > 0.f) ? o0 : (__expf(o0) - 1.f);
  float r1 = (o1 > 0.f) ? o1 : (__expf(o1) - 1.f);
  outp[(size_t)n * 128 + lane] = r0;
  outp[(size_t)n * 128 + 64 + lane] = r1;
}

// ---------------- launch ----------------
extern "C" void kernel_launch(void* const* d_in, const int* in_sizes, int n_in, void* d_out,
                              int out_size, void* d_ws, size_t ws_size, hipStream_t stream) {
  const int* edge_index = (const int*)d_in[0];
  const int* srcA = edge_index;
  const int* dstA = edge_index + ETOT;
  const float* x = (const float*)d_in[1];
  const float* r = (const float*)d_in[2];
  const int* et = (const int*)d_in[3];
  const int* et2 = (const int*)d_in[4];
  const float* Wh = (const float*)d_in[5];
  const float* ah = (const float*)d_in[6];
  const float* Wo = (const float*)d_in[7];
  const float* ao = (const float*)d_in[8];
  const float* Wr = (const float*)d_in[9];
  float* out = (float*)d_out;
  float* r2out = out + (size_t)NNODES * 128;

  // workspace layout (floats)
  float* fws = (float*)d_ws;
  size_t off = 0;
  float* xW = fws + off;    off += (size_t)NNODES * 256;   // shared by layer1/layer2
  float* x1 = fws + off;    off += (size_t)NNODES * 128;
  float* sc1 = fws + off;   off += (size_t)NNODES * 4;
  float* sc2 = fws + off;   off += (size_t)NNODES * 2;
  float* rW1 = fws + off;   off += (size_t)2 * NREL * 64;
  float* srel1 = fws + off; off += 2 * NREL;
  float* rW2 = fws + off;   off += (size_t)NREL * 128;
  float* srel2 = fws + off; off += NREL;
  float* Wp1 = fws + off;   off += 128 * 256;
  float* Wp2 = fws + off;   off += 128 * 256;
  int* iws = (int*)(fws + off);
  int* cnt = iws;
  int* rowstart = cnt + NNODES;        // NNODES+1
  int* cursor = rowstart + NNODES + 1;
  int* blockTot = cursor + NNODES;
  int* blockOff = blockTot + 512;
  int* perm = blockOff + 512;

  // --- CSR build ---
  k_zero_int<<<(NNODES + 255) / 256, 256, 0, stream>>>(cnt, NNODES);
  k_count<<<(ETOT + 255) / 256, 256, 0, stream>>>(srcA, cnt);
  k_scan_a<<<NB_SCAN, 256, 0, stream>>>(cnt, rowstart, blockTot);
  k_scan_b<<<1, 512, 0, stream>>>(blockTot, blockOff);
  k_scan_c<<<NB_SCAN, 256, 0, stream>>>(rowstart, blockOff, cursor);
  k_scatter<<<(ETOT + 255) / 256, 256, 0, stream>>>(srcA, cursor, perm);

  // --- relation precompute ---
  k_relprep1<<<2 * NREL, 64, 0, stream>>>(r, Wh, ah, rW1, srel1);
  k_r2<<<NREL, 128, 0, stream>>>(r, Wr, r2out);
  k_relprep2<<<NREL, 128, 0, stream>>>(r2out, Wo, ao, rW2, srel2);

  // --- layer 1 ---
  k_pack1<<<128, 256, 0, stream>>>(Wh, Wp1);
  k_gemm<<<NNODES / 32, 256, 0, stream>>>(x, Wp1, xW);
  k_scal1<<<NNODES / 4, 256, 0, stream>>>(xW, ah, sc1);
  k_agg1<<<(2 * NNODES) / 4, 256, 0, stream>>>(rowstart, perm, dstA, et, et2, xW, sc1, rW1,
                                               srel1, x1);

  // --- layer 2 ---
  k_pack2<<<128, 256, 0, stream>>>(Wo, Wp2);
  k_gemm<<<NNODES / 32, 256, 0, stream>>>(x1, Wp2, xW);
  k_scal2<<<NNODES / 4, 256, 0, stream>>>(xW, ao, sc2);
  k_agg2<<<NNODES / 4, 256, 0, stream>>>(rowstart, perm, dstA, et, et2, xW, sc2, rW2, srel2,
                                         out);
}

// Round 4
// 596.678 us; speedup vs baseline: 1.3939x; 1.3939x over previous
//
#include <hip/hip_runtime.h>
#include <math.h>

// Problem constants (from reference)
#define NNODES 100000
#define NREL 500
#define E1 288000
#define ETOT 320000
#define LALPHA 0.2f
#define SEPS 1e-16f
#define NB_SCAN ((NNODES + 255) / 256)  // 391 blocks of 256 for the scan

// ---------------- wave (64-lane) reductions ----------------
__device__ __forceinline__ float wave_max64(float v) {
#pragma unroll
  for (int o = 32; o >= 1; o >>= 1) v = fmaxf(v, __shfl_xor(v, o, 64));
  return v;
}
__device__ __forceinline__ float wave_sum64(float v) {
#pragma unroll
  for (int o = 32; o >= 1; o >>= 1) v += __shfl_xor(v, o, 64);
  return v;
}

// ---------------- CSR build ----------------
__global__ void k_zero_int(int* __restrict__ p, int n) {
  int i = blockIdx.x * blockDim.x + threadIdx.x;
  if (i < n) p[i] = 0;
}

__global__ void k_count(const int* __restrict__ src, int* __restrict__ cnt) {
  int e = blockIdx.x * blockDim.x + threadIdx.x;
  if (e < ETOT) atomicAdd(&cnt[src[e]], 1);
}

__global__ void k_scan_a(const int* __restrict__ cnt, int* __restrict__ rowstart,
                         int* __restrict__ blockTot) {
  __shared__ int s[256];
  int t = threadIdx.x;
  int idx = blockIdx.x * 256 + t;
  int v = (idx < NNODES) ? cnt[idx] : 0;
  s[t] = v;
  __syncthreads();
  for (int off = 1; off < 256; off <<= 1) {
    int xv = (t >= off) ? s[t - off] : 0;
    __syncthreads();
    s[t] += xv;
    __syncthreads();
  }
  if (idx < NNODES) rowstart[idx] = s[t] - v;  // exclusive within block
  if (t == 255) blockTot[blockIdx.x] = s[255];
}

__global__ void k_scan_b(const int* __restrict__ blockTot, int* __restrict__ blockOff) {
  __shared__ int s[512];
  int t = threadIdx.x;
  int v = (t < NB_SCAN) ? blockTot[t] : 0;
  s[t] = v;
  __syncthreads();
  for (int off = 1; off < 512; off <<= 1) {
    int xv = (t >= off) ? s[t - off] : 0;
    __syncthreads();
    s[t] += xv;
    __syncthreads();
  }
  if (t < NB_SCAN) blockOff[t] = s[t] - v;  // exclusive
}

__global__ void k_scan_c(int* __restrict__ rowstart, const int* __restrict__ blockOff,
                         int* __restrict__ cursor) {
  int idx = blockIdx.x * 256 + threadIdx.x;
  if (idx < NNODES) {
    int v = rowstart[idx] + blockOff[blockIdx.x];
    rowstart[idx] = v;
    cursor[idx] = v;
  }
  if (idx == 0) rowstart[NNODES] = ETOT;
}

__global__ void k_scatter(const int* __restrict__ src, int* __restrict__ cursor,
                          int* __restrict__ perm) {
  int e = blockIdx.x * blockDim.x + threadIdx.x;
  if (e < ETOT) {
    int pos = atomicAdd(&cursor[src[e]], 1);
    perm[pos] = e;
  }
}

// ---------------- relation-level precompute ----------------
// rW1[t][h][k] = sum_d r[t][d] * W_heads[h][256+d][k]; srel1[t][h] = rW1 . a_heads[h]
__global__ void k_relprep1(const float* __restrict__ r, const float* __restrict__ Wh,
                           const float* __restrict__ ah, float* __restrict__ rW1,
                           float* __restrict__ srel1) {
  int b = blockIdx.x;           // 0..999
  int h = b / NREL;             // 0..1
  int t = b - h * NREL;         // 0..499
  int k = threadIdx.x;          // 0..63
  const float* wcol = Wh + h * 24576 + 256 * 64 + k;
  const float* rrow = r + t * 128;
  float acc = 0.f;
#pragma unroll 4
  for (int d = 0; d < 128; ++d) acc = fmaf(rrow[d], wcol[d * 64], acc);
  rW1[(size_t)t * 128 + h * 64 + k] = acc;
  float p = wave_sum64(acc * ah[h * 64 + k]);
  if (k == 0) srel1[t * 2 + h] = p;
}

// r2[t][c] = sum_d r[t][d] * W_r[d][c]   (also one of the two outputs)
__global__ void k_r2(const float* __restrict__ r, const float* __restrict__ Wr,
                     float* __restrict__ r2out) {
  int t = blockIdx.x;   // 0..499
  int c = threadIdx.x;  // 0..127
  float acc = 0.f;
#pragma unroll 4
  for (int d = 0; d < 128; ++d) acc = fmaf(r[t * 128 + d], Wr[d * 128 + c], acc);
  r2out[t * 128 + c] = acc;
}

// rW2[t][k] = sum_d r2[t][d] * W_out[256+d][k]; srel2[t] = rW2 . a_out
__global__ void k_relprep2(const float* __restrict__ r2, const float* __restrict__ Wo,
                           const float* __restrict__ ao, float* __restrict__ rW2,
                           float* __restrict__ srel2) {
  __shared__ float s[128];
  int t = blockIdx.x;   // 0..499
  int k = threadIdx.x;  // 0..127
  float acc = 0.f;
#pragma unroll 4
  for (int d = 0; d < 128; ++d) acc = fmaf(r2[t * 128 + d], Wo[(256 + d) * 128 + k], acc);
  rW2[(size_t)t * 128 + k] = acc;
  s[k] = acc * ao[k];
  __syncthreads();
  for (int off = 64; off >= 1; off >>= 1) {
    if (k < off) s[k] += s[k + off];
    __syncthreads();
  }
  if (k == 0) srel2[t] = s[0];
}

// ---------------- W packing (d-major for coalesced GEMM reads) ----------------
// Layer1 cols: c = part*128 + h*64 + k  (part 0 = src block, 1 = dst block)
__global__ void k_pack1(const float* __restrict__ Wh, float* __restrict__ Wp) {
  int d = blockIdx.x;   // 0..127
  int c = threadIdx.x;  // 0..255
  int part = c >> 7, h = (c >> 6) & 1, k = c & 63;
  Wp[d * 256 + c] = Wh[h * 24576 + (part * 128 + d) * 64 + k];
}
// Layer2 cols: c = part*128 + k
__global__ void k_pack2(const float* __restrict__ Wo, float* __restrict__ Wp) {
  int d = blockIdx.x;
  int c = threadIdx.x;
  int part = c >> 7, k = c & 127;
  Wp[d * 256 + c] = Wo[(part * 128 + d) * 128 + k];
}

// ---------------- node-level GEMM: Y[N][256] = X[N][128] @ Wp[128][256] ----------------
// Fused epilogue: sc[n][slot] = sum_c Y[n][c]*avec(c) grouped by slot(c).
// LAYER==1: slot = h*2+part (4 slots), avec = ah[h*64+k].
// LAYER==2: slot = part (2 slots), avec = ao[k].
template <int LAYER>
__global__ __launch_bounds__(256) void k_gemm(const float* __restrict__ X,
                                              const float* __restrict__ Wp,
                                              const float* __restrict__ avec,
                                              float* __restrict__ Y, float* __restrict__ sc) {
  __shared__ float xs[32][128];
  __shared__ float sred[8][4][4];
  const int t = threadIdx.x;
  if (t < 128) ((float*)sred)[t] = 0.f;
  const size_t nbase = (size_t)blockIdx.x * 32;  // 100000 = 32*3125, exact
  const float4* Xv = (const float4*)(X + nbase * 128);
  float4* sv = (float4*)(&xs[0][0]);
#pragma unroll
  for (int i = 0; i < 4; ++i) sv[t + i * 256] = Xv[t + i * 256];
  __syncthreads();
  const int cg = t & 31, ng = t >> 5;
  const int c0 = cg * 8, n0 = ng * 4;
  float acc[4][8];
#pragma unroll
  for (int i = 0; i < 4; ++i)
#pragma unroll
    for (int j = 0; j < 8; ++j) acc[i][j] = 0.f;

  for (int d = 0; d < 128; d += 4) {
    float xv[4][4];
#pragma unroll
    for (int i = 0; i < 4; ++i) *(float4*)&xv[i][0] = *(const float4*)&xs[n0 + i][d];
#pragma unroll
    for (int dd = 0; dd < 4; ++dd) {
      float4 wa = *(const float4*)(Wp + (d + dd) * 256 + c0);
      float4 wb = *(const float4*)(Wp + (d + dd) * 256 + c0 + 4);
      float w[8] = {wa.x, wa.y, wa.z, wa.w, wb.x, wb.y, wb.z, wb.w};
#pragma unroll
      for (int i = 0; i < 4; ++i)
#pragma unroll
        for (int j = 0; j < 8; ++j) acc[i][j] = fmaf(xv[i][dd], w[j], acc[i][j]);
    }
  }
  // store Y
#pragma unroll
  for (int i = 0; i < 4; ++i) {
    float* yp = Y + (nbase + n0 + i) * 256 + c0;
    *(float4*)yp = make_float4(acc[i][0], acc[i][1], acc[i][2], acc[i][3]);
    *(float4*)(yp + 4) = make_float4(acc[i][4], acc[i][5], acc[i][6], acc[i][7]);
  }
  // fused attention-scalar epilogue
  int slot;
  float av[8];
  if (LAYER == 1) {
    int h = (c0 >> 6) & 1, part = c0 >> 7;
    slot = h * 2 + part;
#pragma unroll
    for (int j = 0; j < 8; ++j) av[j] = avec[h * 64 + ((c0 + j) & 63)];
  } else {
    slot = c0 >> 7;
#pragma unroll
    for (int j = 0; j < 8; ++j) av[j] = avec[(c0 + j) & 127];
  }
#pragma unroll
  for (int i = 0; i < 4; ++i) {
    float p = 0.f;
#pragma unroll
    for (int j = 0; j < 8; ++j) p = fmaf(acc[i][j], av[j], p);
    atomicAdd(&sred[ng][i][slot], p);
  }
  __syncthreads();
  if (LAYER == 1) {
    if (t < 128) {
      int node = t >> 2, s = t & 3;
      sc[(nbase + node) * 4 + s] = sred[node >> 2][node & 3][s];
    }
  } else {
    if (t < 64) {
      int node = t >> 1, s = t & 1;
      sc[(nbase + node) * 2 + s] = sred[node >> 2][node & 3][s];
    }
  }
}

// ---------------- layer-1 aggregation: one wave per node, both heads, online softmax ----
__global__ __launch_bounds__(256) void k_agg1(
    const int* __restrict__ rowstart, const int* __restrict__ perm,
    const int* __restrict__ dstA, const int* __restrict__ et, const int* __restrict__ et2,
    const float* __restrict__ xW, const float* __restrict__ sc1,
    const float* __restrict__ rW1, const float* __restrict__ srel1, float* __restrict__ x1) {
  int n = blockIdx.x * 4 + (threadIdx.x >> 6);
  int lane = threadIdx.x & 63;
  int s0 = rowstart[n];
  int deg = rowstart[n + 1] - s0;
  float r0 = 0.f, r1 = 0.f;
  if (deg > 0) {
    float4 scn = ((const float4*)sc1)[n];
    const float ss0 = scn.x, ss1 = scn.z;
    float m0 = -3.4e38f, m1 = -3.4e38f, d0 = 0.f, d1 = 0.f, acc0 = 0.f, acc1 = 0.f;
    for (int base = 0; base < deg; base += 64) {
      int i = base + lane;
      int dn = 0, t1 = 0, t2 = -1;
      float lg0 = -3.4e38f, lg1 = -3.4e38f;
      if (i < deg) {
        int ed = perm[s0 + i];
        dn = dstA[ed];
        float rel0, rel1;
        if (ed < E1) {
          t1 = et[ed];
          float2 sr = ((const float2*)srel1)[t1];
          rel0 = sr.x;
          rel1 = sr.y;
        } else {
          int j = ed - E1;
          t1 = et2[2 * j];
          t2 = et2[2 * j + 1];
          float2 sa = ((const float2*)srel1)[t1];
          float2 sb = ((const float2*)srel1)[t2];
          rel0 = sa.x + sb.x;
          rel1 = sa.y + sb.y;
        }
        float4 scd = ((const float4*)sc1)[dn];
        float e0 = ss0 + scd.y + rel0;
        float e1 = ss1 + scd.w + rel1;
        lg0 = (e0 >= 0.f) ? e0 : LALPHA * e0;
        lg1 = (e1 >= 0.f) ? e1 : LALPHA * e1;
      }
      float nm0 = fmaxf(m0, wave_max64(lg0));
      float nm1 = fmaxf(m1, wave_max64(lg1));
      float rs0 = __expf(m0 - nm0), rs1 = __expf(m1 - nm1);
      float w0 = __expf(lg0 - nm0), w1 = __expf(lg1 - nm1);  // invalid lanes -> 0
      d0 = d0 * rs0 + wave_sum64(w0);
      d1 = d1 * rs1 + wave_sum64(w1);
      acc0 *= rs0;
      acc1 *= rs1;
      m0 = nm0;
      m1 = nm1;
      int cnt = min(64, deg - base);
      for (int e2 = 0; e2 < cnt; ++e2) {
        float a0 = __shfl(w0, e2, 64);
        float a1 = __shfl(w1, e2, 64);
        int dne = __shfl(dn, e2, 64);
        int t1e = __shfl(t1, e2, 64);
        int t2e = __shfl(t2, e2, 64);
        const float* rp = rW1 + (size_t)t1e * 128;
        float rv0 = rp[lane], rv1 = rp[64 + lane];
        if (t2e >= 0) {  // wave-uniform branch
          const float* rq = rW1 + (size_t)t2e * 128;
          rv0 += rq[lane];
          rv1 += rq[64 + lane];
        }
        const float* dw = xW + (size_t)dne * 256 + 128;
        acc0 = fmaf(a0, dw[lane] + rv0, acc0);
        acc1 = fmaf(a1, dw[64 + lane] + rv1, acc1);
      }
    }
    float inv0 = 1.f / (d0 + SEPS), inv1 = 1.f / (d1 + SEPS);
    float src0 = xW[(size_t)n * 256 + lane];
    float src1 = xW[(size_t)n * 256 + 64 + lane];
    float o0 = (acc0 + d0 * src0) * inv0;
    float o1 = (acc1 + d1 * src1) * inv1;
    r0 = (o0 > 0.f) ? o0 : __expf(o0) - 1.f;  // elu (concat=True)
    r1 = (o1 > 0.f) ? o1 : __expf(o1) - 1.f;
  }
  x1[(size_t)n * 128 + lane] = r0;
  x1[(size_t)n * 128 + 64 + lane] = r1;
}

// ---------------- layer-2 aggregation: one wave per node, 128 dims, online softmax ----
__global__ __launch_bounds__(256) void k_agg2(
    const int* __restrict__ rowstart, const int* __restrict__ perm,
    const int* __restrict__ dstA, const int* __restrict__ et, const int* __restrict__ et2,
    const float* __restrict__ xW, const float* __restrict__ sc2,
    const float* __restrict__ rW2, const float* __restrict__ srel2, float* __restrict__ outp) {
  int n = blockIdx.x * 4 + (threadIdx.x >> 6);
  int lane = threadIdx.x & 63;
  int s0 = rowstart[n];
  int deg = rowstart[n + 1] - s0;
  float r0 = 0.f, r1 = 0.f;
  if (deg > 0) {
    const float ss = ((const float2*)sc2)[n].x;
    float m = -3.4e38f, d = 0.f, acc0 = 0.f, acc1 = 0.f;
    for (int base = 0; base < deg; base += 64) {
      int i = base + lane;
      int dn = 0, t1 = 0, t2 = -1;
      float lg = -3.4e38f;
      if (i < deg) {
        int ed = perm[s0 + i];
        dn = dstA[ed];
        float rel;
        if (ed < E1) {
          t1 = et[ed];
          rel = srel2[t1];
        } else {
          int j = ed - E1;
          t1 = et2[2 * j];
          t2 = et2[2 * j + 1];
          rel = srel2[t1] + srel2[t2];
        }
        float e = ss + ((const float2*)sc2)[dn].y + rel;
        lg = (e >= 0.f) ? e : LALPHA * e;
      }
      float nm = fmaxf(m, wave_max64(lg));
      float rs = __expf(m - nm);
      float w = __expf(lg - nm);
      d = d * rs + wave_sum64(w);
      acc0 *= rs;
      acc1 *= rs;
      m = nm;
      int cnt = min(64, deg - base);
      for (int e2 = 0; e2 < cnt; ++e2) {
        float a = __shfl(w, e2, 64);
        int dne = __shfl(dn, e2, 64);
        int t1e = __shfl(t1, e2, 64);
        int t2e = __shfl(t2, e2, 64);
        const float* rp = rW2 + (size_t)t1e * 128;
        float rv0 = rp[lane], rv1 = rp[64 + lane];
        if (t2e >= 0) {
          const float* rq = rW2 + (size_t)t2e * 128;
          rv0 += rq[lane];
          rv1 += rq[64 + lane];
        }
        const float* dw = xW + (size_t)dne * 256 + 128;
        acc0 = fmaf(a, dw[lane] + rv0, acc0);
        acc1 = fmaf(a, dw[64 + lane] + rv1, acc1);
      }
    }
    float inv = 1.f / (d + SEPS);
    float src0 = xW[(size_t)n * 256 + lane];
    float src1 = xW[(size_t)n * 256 + 64 + lane];
    float o0 = (acc0 + d * src0) * inv;
    float o1 = (acc1 + d * src1) * inv;
    r0 = (o0 > 0.f) ? o0 : __expf(o0) - 1.f;  // final elu
    r1 = (o1 > 0.f) ? o1 : __expf(o1) - 1.f;
  }
  outp[(size_t)n * 128 + lane] = r0;
  outp[(size_t)n * 128 + 64 + lane] = r1;
}

// ---------------- launch ----------------
extern "C" void kernel_launch(void* const* d_in, const int* in_sizes, int n_in, void* d_out,
                              int out_size, void* d_ws, size_t ws_size, hipStream_t stream) {
  const int* edge_index = (const int*)d_in[0];
  const int* srcA = edge_index;
  const int* dstA = edge_index + ETOT;
  const float* x = (const float*)d_in[1];
  const float* r = (const float*)d_in[2];
  const int* et = (const int*)d_in[3];
  const int* et2 = (const int*)d_in[4];
  const float* Wh = (const float*)d_in[5];
  const float* ah = (const float*)d_in[6];
  const float* Wo = (const float*)d_in[7];
  const float* ao = (const float*)d_in[8];
  const float* Wr = (const float*)d_in[9];
  float* out = (float*)d_out;
  float* r2out = out + (size_t)NNODES * 128;

  // workspace layout (floats)
  float* fws = (float*)d_ws;
  size_t off = 0;
  float* xW = fws + off;    off += (size_t)NNODES * 256;   // shared by layer1/layer2
  float* x1 = fws + off;    off += (size_t)NNODES * 128;
  float* sc1 = fws + off;   off += (size_t)NNODES * 4;
  float* sc2 = fws + off;   off += (size_t)NNODES * 2;
  float* rW1 = fws + off;   off += (size_t)NREL * 128;     // [t][h][64]
  float* srel1 = fws + off; off += 2 * NREL;               // [t][h] pairs
  float* rW2 = fws + off;   off += (size_t)NREL * 128;
  float* srel2 = fws + off; off += NREL;
  float* Wp1 = fws + off;   off += 128 * 256;
  float* Wp2 = fws + off;   off += 128 * 256;
  int* iws = (int*)(fws + off);
  int* cnt = iws;
  int* rowstart = cnt + NNODES;        // NNODES+1
  int* cursor = rowstart + NNODES + 1;
  int* blockTot = cursor + NNODES;
  int* blockOff = blockTot + 512;
  int* perm = blockOff + 512;

  // --- CSR build ---
  k_zero_int<<<(NNODES + 255) / 256, 256, 0, stream>>>(cnt, NNODES);
  k_count<<<(ETOT + 255) / 256, 256, 0, stream>>>(srcA, cnt);
  k_scan_a<<<NB_SCAN, 256, 0, stream>>>(cnt, rowstart, blockTot);
  k_scan_b<<<1, 512, 0, stream>>>(blockTot, blockOff);
  k_scan_c<<<NB_SCAN, 256, 0, stream>>>(rowstart, blockOff, cursor);
  k_scatter<<<(ETOT + 255) / 256, 256, 0, stream>>>(srcA, cursor, perm);

  // --- relation precompute ---
  k_relprep1<<<2 * NREL, 64, 0, stream>>>(r, Wh, ah, rW1, srel1);
  k_r2<<<NREL, 128, 0, stream>>>(r, Wr, r2out);
  k_relprep2<<<NREL, 128, 0, stream>>>(r2out, Wo, ao, rW2, srel2);

  // --- layer 1 ---
  k_pack1<<<128, 256, 0, stream>>>(Wh, Wp1);
  k_gemm<1><<<NNODES / 32, 256, 0, stream>>>(x, Wp1, ah, xW, sc1);
  k_agg1<<<NNODES / 4, 256, 0, stream>>>(rowstart, perm, dstA, et, et2, xW, sc1, rW1, srel1,
                                         x1);

  // --- layer 2 ---
  k_pack2<<<128, 256, 0, stream>>>(Wo, Wp2);
  k_gemm<2><<<NNODES / 32, 256, 0, stream>>>(x1, Wp2, ao, xW, sc2);
  k_agg2<<<NNODES / 4, 256, 0, stream>>>(rowstart, perm, dstA, et, et2, xW, sc2, rW2, srel2,
                                         out);
}

// Round 5
// 489.869 us; speedup vs baseline: 1.6978x; 1.2180x over previous
//
#include <hip/hip_runtime.h>
#include <math.h>

// Problem constants (from reference)
#define NNODES 100000
#define NREL 500
#define E1 288000
#define ETOT 320000
#define LALPHA 0.2f
#define SEPS 1e-16f
#define NB_SCAN ((NNODES + 255) / 256)  // 391 blocks of 256 for the scan

typedef __attribute__((ext_vector_type(8))) short bf16x8;
typedef __attribute__((ext_vector_type(4))) float f32x4;

// fp32 -> bf16 (round-to-nearest-even), header-independent
__device__ __forceinline__ unsigned short f2bf(float x) {
  unsigned int u = __float_as_uint(x);
  unsigned int r = (u + 0x7fffu + ((u >> 16) & 1u)) >> 16;
  return (unsigned short)r;
}

// ---------------- wave (64-lane) reductions ----------------
__device__ __forceinline__ float wave_max64(float v) {
#pragma unroll
  for (int o = 32; o >= 1; o >>= 1) v = fmaxf(v, __shfl_xor(v, o, 64));
  return v;
}
__device__ __forceinline__ float wave_sum64(float v) {
#pragma unroll
  for (int o = 32; o >= 1; o >>= 1) v += __shfl_xor(v, o, 64);
  return v;
}

// ---------------- CSR build ----------------
__global__ void k_zero_int(int* __restrict__ p, int n) {
  int i = blockIdx.x * blockDim.x + threadIdx.x;
  if (i < n) p[i] = 0;
}

__global__ void k_count(const int* __restrict__ src, int* __restrict__ cnt) {
  int e = blockIdx.x * blockDim.x + threadIdx.x;
  if (e < ETOT) atomicAdd(&cnt[src[e]], 1);
}

__global__ void k_scan_a(const int* __restrict__ cnt, int* __restrict__ rowstart,
                         int* __restrict__ blockTot) {
  __shared__ int s[256];
  int t = threadIdx.x;
  int idx = blockIdx.x * 256 + t;
  int v = (idx < NNODES) ? cnt[idx] : 0;
  s[t] = v;
  __syncthreads();
  for (int off = 1; off < 256; off <<= 1) {
    int xv = (t >= off) ? s[t - off] : 0;
    __syncthreads();
    s[t] += xv;
    __syncthreads();
  }
  if (idx < NNODES) rowstart[idx] = s[t] - v;  // exclusive within block
  if (t == 255) blockTot[blockIdx.x] = s[255];
}

__global__ void k_scan_b(const int* __restrict__ blockTot, int* __restrict__ blockOff) {
  __shared__ int s[512];
  int t = threadIdx.x;
  int v = (t < NB_SCAN) ? blockTot[t] : 0;
  s[t] = v;
  __syncthreads();
  for (int off = 1; off < 512; off <<= 1) {
    int xv = (t >= off) ? s[t - off] : 0;
    __syncthreads();
    s[t] += xv;
    __syncthreads();
  }
  if (t < NB_SCAN) blockOff[t] = s[t] - v;  // exclusive
}

__global__ void k_scan_c(int* __restrict__ rowstart, const int* __restrict__ blockOff,
                         int* __restrict__ cursor) {
  int idx = blockIdx.x * 256 + threadIdx.x;
  if (idx < NNODES) {
    int v = rowstart[idx] + blockOff[blockIdx.x];
    rowstart[idx] = v;
    cursor[idx] = v;
  }
  if (idx == 0) rowstart[NNODES] = ETOT;
}

__global__ void k_scatter(const int* __restrict__ src, int* __restrict__ cursor,
                          int* __restrict__ perm) {
  int e = blockIdx.x * blockDim.x + threadIdx.x;
  if (e < ETOT) {
    int pos = atomicAdd(&cursor[src[e]], 1);
    perm[pos] = e;
  }
}

// ---------------- relation-level precompute (fp32, tiny) ----------------
// rW1[t][h][k] = sum_d r[t][d] * W_heads[h][256+d][k]; srel1[t][h] = rW1 . a_heads[h]
__global__ void k_relprep1(const float* __restrict__ r, const float* __restrict__ Wh,
                           const float* __restrict__ ah, float* __restrict__ rW1,
                           float* __restrict__ srel1) {
  int b = blockIdx.x;           // 0..999
  int h = b / NREL;             // 0..1
  int t = b - h * NREL;         // 0..499
  int k = threadIdx.x;          // 0..63
  const float* wcol = Wh + h * 24576 + 256 * 64 + k;
  const float* rrow = r + t * 128;
  float acc = 0.f;
#pragma unroll 4
  for (int d = 0; d < 128; ++d) acc = fmaf(rrow[d], wcol[d * 64], acc);
  rW1[(size_t)t * 128 + h * 64 + k] = acc;
  float p = wave_sum64(acc * ah[h * 64 + k]);
  if (k == 0) srel1[t * 2 + h] = p;
}

// r2[t][c] = sum_d r[t][d] * W_r[d][c]   (also one of the two outputs)
__global__ void k_r2(const float* __restrict__ r, const float* __restrict__ Wr,
                     float* __restrict__ r2out) {
  int t = blockIdx.x;   // 0..499
  int c = threadIdx.x;  // 0..127
  float acc = 0.f;
#pragma unroll 4
  for (int d = 0; d < 128; ++d) acc = fmaf(r[t * 128 + d], Wr[d * 128 + c], acc);
  r2out[t * 128 + c] = acc;
}

// rW2[t][k] = sum_d r2[t][d] * W_out[256+d][k]; srel2[t] = rW2 . a_out
__global__ void k_relprep2(const float* __restrict__ r2, const float* __restrict__ Wo,
                           const float* __restrict__ ao, float* __restrict__ rW2,
                           float* __restrict__ srel2) {
  __shared__ float s[128];
  int t = blockIdx.x;   // 0..499
  int k = threadIdx.x;  // 0..127
  float acc = 0.f;
#pragma unroll 4
  for (int d = 0; d < 128; ++d) acc = fmaf(r2[t * 128 + d], Wo[(256 + d) * 128 + k], acc);
  rW2[(size_t)t * 128 + k] = acc;
  s[k] = acc * ao[k];
  __syncthreads();
  for (int off = 64; off >= 1; off >>= 1) {
    if (k < off) s[k] += s[k + off];
    __syncthreads();
  }
  if (k == 0) srel2[t] = s[0];
}

// ---------------- bf16 conversion & weight packing ----------------
// x (fp32, n8*8 elems) -> bf16
__global__ void k_cvt(const float* __restrict__ in, unsigned short* __restrict__ out, int n8) {
  int i = blockIdx.x * blockDim.x + threadIdx.x;
  if (i < n8) {
    float4 v0 = ((const float4*)in)[i * 2];
    float4 v1 = ((const float4*)in)[i * 2 + 1];
    union {
      unsigned short u[8];
      uint4 q;
    } o;
    o.u[0] = f2bf(v0.x); o.u[1] = f2bf(v0.y); o.u[2] = f2bf(v0.z); o.u[3] = f2bf(v0.w);
    o.u[4] = f2bf(v1.x); o.u[5] = f2bf(v1.y); o.u[6] = f2bf(v1.z); o.u[7] = f2bf(v1.w);
    ((uint4*)out)[i] = o.q;
  }
}

// Wb[c][d] (bf16, B^T layout: row = output col c, 128 contiguous k)
// LAYER1: c = part*128 + h*64 + kc -> Wh[h][part*128+d][kc]
// LAYER2: c = part*128 + kc       -> Wo[part*128+d][kc]
template <int LAYER>
__global__ void k_packb(const float* __restrict__ W, unsigned short* __restrict__ Wb) {
  int c = blockIdx.x;   // 0..255
  int d = threadIdx.x;  // 0..127
  float v;
  if (LAYER == 1) {
    int h = (c >> 6) & 1, part = c >> 7, kc = c & 63;
    v = W[h * 24576 + (part * 128 + d) * 64 + kc];
  } else {
    int part = c >> 7, kc = c & 127;
    v = W[(part * 128 + d) * 128 + kc];
  }
  Wb[c * 128 + d] = f2bf(v);
}

// ---------------- MFMA GEMM: Y[N][256] = Xb[N][128] @ Wb^T, fp32 out ----------------
// 4 waves/block, wave handles 16 rows x 256 cols (16 tiles of 16x16, K=128 in 4 steps).
// Fragment layouts (verified m89/m92): A row=lane&15, k=(lane>>4)*8+j contiguous;
// B^T col=lane&15, same k; D col=lane&15, row=(lane>>4)*4+reg.
// Fused epilogue: sc[n][slot] = sum_c Y[n][c]*avec[c&127], slot by col range.
template <int LAYER>
__global__ __launch_bounds__(256) void k_gemm_mfma(const unsigned short* __restrict__ Xb,
                                                   const unsigned short* __restrict__ Wb,
                                                   const float* __restrict__ avec,
                                                   float* __restrict__ Y,
                                                   float* __restrict__ sc) {
  const int lane = threadIdx.x & 63;
  const int wave = threadIdx.x >> 6;
  const int rb = blockIdx.x * 64 + wave * 16;  // wave's first row
  const int colv = lane & 15;
  const int kg = lane >> 4;  // k-group / row-group

  // A fragments: row clamped (tail block), 4 K-steps
  int ar = rb + colv;
  ar = (ar < NNODES) ? ar : (NNODES - 1);
  const unsigned short* ap = Xb + (size_t)ar * 128 + kg * 8;
  bf16x8 a[4];
#pragma unroll
  for (int s = 0; s < 4; ++s) a[s] = *(const bf16x8*)(ap + s * 32);

  f32x4 acc[16];
#pragma unroll
  for (int t = 0; t < 16; ++t) acc[t] = (f32x4){0.f, 0.f, 0.f, 0.f};

#pragma unroll
  for (int t = 0; t < 16; ++t) {
    const unsigned short* wp = Wb + (size_t)(t * 16 + colv) * 128 + kg * 8;
#pragma unroll
    for (int s = 0; s < 4; ++s) {
      bf16x8 b = *(const bf16x8*)(wp + s * 32);
      acc[t] = __builtin_amdgcn_mfma_f32_16x16x32_bf16(a[s], b, acc[t], 0, 0, 0);
    }
  }

  // ---- store Y + attention-scalar epilogue ----
  const int NS = (LAYER == 1) ? 4 : 2;
  float psum[4][4];
#pragma unroll
  for (int i = 0; i < 4; ++i)
#pragma unroll
    for (int s = 0; s < 4; ++s) psum[i][s] = 0.f;

#pragma unroll
  for (int t = 0; t < 16; ++t) {
    int c = t * 16 + colv;
    float av = avec[c & 127];
    int slot = (LAYER == 1) ? (((c >> 6) & 1) * 2 + (c >> 7)) : (c >> 7);
    int grow = rb + kg * 4;
#pragma unroll
    for (int i = 0; i < 4; ++i) {
      float v = acc[t][i];
      if (grow + i < NNODES) Y[(size_t)(grow + i) * 256 + c] = v;
      psum[i][slot] = fmaf(v, av, psum[i][slot]);
    }
  }
  // reduce psum across the 16 lanes of each row-group (same kg)
#pragma unroll
  for (int i = 0; i < 4; ++i)
#pragma unroll
    for (int s = 0; s < 4; ++s) {
      if (s < NS) {
        float v = psum[i][s];
        v += __shfl_xor(v, 1, 64);
        v += __shfl_xor(v, 2, 64);
        v += __shfl_xor(v, 4, 64);
        v += __shfl_xor(v, 8, 64);
        psum[i][s] = v;
      }
    }
  if (colv == 0) {
    int grow = rb + kg * 4;
#pragma unroll
    for (int i = 0; i < 4; ++i) {
      if (grow + i < NNODES) {
#pragma unroll
        for (int s = 0; s < 4; ++s)
          if (s < NS) sc[(size_t)(grow + i) * NS + s] = psum[i][s];
      }
    }
  }
}

// ---------------- layer-1 aggregation: one wave per node, both heads, online softmax ----
// writes x1 in bf16 (only consumed by GEMM2)
__global__ __launch_bounds__(256) void k_agg1(
    const int* __restrict__ rowstart, const int* __restrict__ perm,
    const int* __restrict__ dstA, const int* __restrict__ et, const int* __restrict__ et2,
    const float* __restrict__ xW, const float* __restrict__ sc1,
    const float* __restrict__ rW1, const float* __restrict__ srel1,
    unsigned short* __restrict__ x1b) {
  int n = blockIdx.x * 4 + (threadIdx.x >> 6);
  int lane = threadIdx.x & 63;
  int s0 = rowstart[n];
  int deg = rowstart[n + 1] - s0;
  float r0 = 0.f, r1 = 0.f;
  if (deg > 0) {
    float4 scn = ((const float4*)sc1)[n];
    const float ss0 = scn.x, ss1 = scn.z;
    float m0 = -3.4e38f, m1 = -3.4e38f, d0 = 0.f, d1 = 0.f, acc0 = 0.f, acc1 = 0.f;
    for (int base = 0; base < deg; base += 64) {
      int i = base + lane;
      int dn = 0, t1 = 0, t2 = -1;
      float lg0 = -3.4e38f, lg1 = -3.4e38f;
      if (i < deg) {
        int ed = perm[s0 + i];
        dn = dstA[ed];
        float rel0, rel1;
        if (ed < E1) {
          t1 = et[ed];
          float2 sr = ((const float2*)srel1)[t1];
          rel0 = sr.x;
          rel1 = sr.y;
        } else {
          int j = ed - E1;
          t1 = et2[2 * j];
          t2 = et2[2 * j + 1];
          float2 sa = ((const float2*)srel1)[t1];
          float2 sb = ((const float2*)srel1)[t2];
          rel0 = sa.x + sb.x;
          rel1 = sa.y + sb.y;
        }
        float4 scd = ((const float4*)sc1)[dn];
        float e0 = ss0 + scd.y + rel0;
        float e1 = ss1 + scd.w + rel1;
        lg0 = (e0 >= 0.f) ? e0 : LALPHA * e0;
        lg1 = (e1 >= 0.f) ? e1 : LALPHA * e1;
      }
      float nm0 = fmaxf(m0, wave_max64(lg0));
      float nm1 = fmaxf(m1, wave_max64(lg1));
      float rs0 = __expf(m0 - nm0), rs1 = __expf(m1 - nm1);
      float w0 = __expf(lg0 - nm0), w1 = __expf(lg1 - nm1);  // invalid lanes -> 0
      d0 = d0 * rs0 + wave_sum64(w0);
      d1 = d1 * rs1 + wave_sum64(w1);
      acc0 *= rs0;
      acc1 *= rs1;
      m0 = nm0;
      m1 = nm1;
      int cnt = min(64, deg - base);
      for (int e2 = 0; e2 < cnt; ++e2) {
        float a0 = __shfl(w0, e2, 64);
        float a1 = __shfl(w1, e2, 64);
        int dne = __shfl(dn, e2, 64);
        int t1e = __shfl(t1, e2, 64);
        int t2e = __shfl(t2, e2, 64);
        const float* rp = rW1 + (size_t)t1e * 128;
        float rv0 = rp[lane], rv1 = rp[64 + lane];
        if (t2e >= 0) {  // wave-uniform branch
          const float* rq = rW1 + (size_t)t2e * 128;
          rv0 += rq[lane];
          rv1 += rq[64 + lane];
        }
        const float* dw = xW + (size_t)dne * 256 + 128;
        acc0 = fmaf(a0, dw[lane] + rv0, acc0);
        acc1 = fmaf(a1, dw[64 + lane] + rv1, acc1);
      }
    }
    float inv0 = 1.f / (d0 + SEPS), inv1 = 1.f / (d1 + SEPS);
    float src0 = xW[(size_t)n * 256 + lane];
    float src1 = xW[(size_t)n * 256 + 64 + lane];
    float o0 = (acc0 + d0 * src0) * inv0;
    float o1 = (acc1 + d1 * src1) * inv1;
    r0 = (o0 > 0.f) ? o0 : __expf(o0) - 1.f;  // elu (concat=True)
    r1 = (o1 > 0.f) ? o1 : __expf(o1) - 1.f;
  }
  x1b[(size_t)n * 128 + lane] = f2bf(r0);
  x1b[(size_t)n * 128 + 64 + lane] = f2bf(r1);
}

// ---------------- layer-2 aggregation: one wave per node, 128 dims, online softmax ----
__global__ __launch_bounds__(256) void k_agg2(
    const int* __restrict__ rowstart, const int* __restrict__ perm,
    const int* __restrict__ dstA, const int* __restrict__ et, const int* __restrict__ et2,
    const float* __restrict__ xW, const float* __restrict__ sc2,
    const float* __restrict__ rW2, const float* __restrict__ srel2, float* __restrict__ outp) {
  int n = blockIdx.x * 4 + (threadIdx.x >> 6);
  int lane = threadIdx.x & 63;
  int s0 = rowstart[n];
  int deg = rowstart[n + 1] - s0;
  float r0 = 0.f, r1 = 0.f;
  if (deg > 0) {
    const float ss = ((const float2*)sc2)[n].x;
    float m = -3.4e38f, d = 0.f, acc0 = 0.f, acc1 = 0.f;
    for (int base = 0; base < deg; base += 64) {
      int i = base + lane;
      int dn = 0, t1 = 0, t2 = -1;
      float lg = -3.4e38f;
      if (i < deg) {
        int ed = perm[s0 + i];
        dn = dstA[ed];
        float rel;
        if (ed < E1) {
          t1 = et[ed];
          rel = srel2[t1];
        } else {
          int j = ed - E1;
          t1 = et2[2 * j];
          t2 = et2[2 * j + 1];
          rel = srel2[t1] + srel2[t2];
        }
        float e = ss + ((const float2*)sc2)[dn].y + rel;
        lg = (e >= 0.f) ? e : LALPHA * e;
      }
      float nm = fmaxf(m, wave_max64(lg));
      float rs = __expf(m - nm);
      float w = __expf(lg - nm);
      d = d * rs + wave_sum64(w);
      acc0 *= rs;
      acc1 *= rs;
      m = nm;
      int cnt = min(64, deg - base);
      for (int e2 = 0; e2 < cnt; ++e2) {
        float a = __shfl(w, e2, 64);
        int dne = __shfl(dn, e2, 64);
        int t1e = __shfl(t1, e2, 64);
        int t2e = __shfl(t2, e2, 64);
        const float* rp = rW2 + (size_t)t1e * 128;
        float rv0 = rp[lane], rv1 = rp[64 + lane];
        if (t2e >= 0) {
          const float* rq = rW2 + (size_t)t2e * 128;
          rv0 += rq[lane];
          rv1 += rq[64 + lane];
        }
        const float* dw = xW + (size_t)dne * 256 + 128;
        acc0 = fmaf(a, dw[lane] + rv0, acc0);
        acc1 = fmaf(a, dw[64 + lane] + rv1, acc1);
      }
    }
    float inv = 1.f / (d + SEPS);
    float src0 = xW[(size_t)n * 256 + lane];
    float src1 = xW[(size_t)n * 256 + 64 + lane];
    float o0 = (acc0 + d * src0) * inv;
    float o1 = (acc1 + d * src1) * inv;
    r0 = (o0 > 0.f) ? o0 : __expf(o0) - 1.f;  // final elu
    r1 = (o1 > 0.f) ? o1 : __expf(o1) - 1.f;
  }
  outp[(size_t)n * 128 + lane] = r0;
  outp[(size_t)n * 128 + 64 + lane] = r1;
}

// ---------------- launch ----------------
extern "C" void kernel_launch(void* const* d_in, const int* in_sizes, int n_in, void* d_out,
                              int out_size, void* d_ws, size_t ws_size, hipStream_t stream) {
  const int* edge_index = (const int*)d_in[0];
  const int* srcA = edge_index;
  const int* dstA = edge_index + ETOT;
  const float* x = (const float*)d_in[1];
  const float* r = (const float*)d_in[2];
  const int* et = (const int*)d_in[3];
  const int* et2 = (const int*)d_in[4];
  const float* Wh = (const float*)d_in[5];
  const float* ah = (const float*)d_in[6];
  const float* Wo = (const float*)d_in[7];
  const float* ao = (const float*)d_in[8];
  const float* Wr = (const float*)d_in[9];
  float* out = (float*)d_out;
  float* r2out = out + (size_t)NNODES * 128;

  // workspace layout
  float* fws = (float*)d_ws;
  size_t off = 0;
  float* xW = fws + off;    off += (size_t)NNODES * 256;   // shared by layer1/layer2
  float* sc1 = fws + off;   off += (size_t)NNODES * 4;
  float* sc2 = fws + off;   off += (size_t)NNODES * 2;
  float* rW1 = fws + off;   off += (size_t)NREL * 128;     // [t][h][64]
  float* srel1 = fws + off; off += 2 * NREL;               // [t][h] pairs
  float* rW2 = fws + off;   off += (size_t)NREL * 128;
  float* srel2 = fws + off; off += NREL + 500;             // +500 pad -> keep 16B alignment
  unsigned short* usws = (unsigned short*)(fws + off);
  size_t uoff = 0;
  unsigned short* Xb = usws + uoff;  uoff += (size_t)NNODES * 128;  // bf16 x
  unsigned short* x1b = usws + uoff; uoff += (size_t)NNODES * 128;  // bf16 x1
  unsigned short* Wb1 = usws + uoff; uoff += 256 * 128;
  unsigned short* Wb2 = usws + uoff; uoff += 256 * 128;
  int* iws = (int*)(usws + uoff);
  int* cnt = iws;
  int* rowstart = cnt + NNODES;        // NNODES+1
  int* cursor = rowstart + NNODES + 1;
  int* blockTot = cursor + NNODES;
  int* blockOff = blockTot + 512;
  int* perm = blockOff + 512;

  // --- CSR build ---
  k_zero_int<<<(NNODES + 255) / 256, 256, 0, stream>>>(cnt, NNODES);
  k_count<<<(ETOT + 255) / 256, 256, 0, stream>>>(srcA, cnt);
  k_scan_a<<<NB_SCAN, 256, 0, stream>>>(cnt, rowstart, blockTot);
  k_scan_b<<<1, 512, 0, stream>>>(blockTot, blockOff);
  k_scan_c<<<NB_SCAN, 256, 0, stream>>>(rowstart, blockOff, cursor);
  k_scatter<<<(ETOT + 255) / 256, 256, 0, stream>>>(srcA, cursor, perm);

  // --- relation precompute + bf16 staging ---
  k_relprep1<<<2 * NREL, 64, 0, stream>>>(r, Wh, ah, rW1, srel1);
  k_r2<<<NREL, 128, 0, stream>>>(r, Wr, r2out);
  k_relprep2<<<NREL, 128, 0, stream>>>(r2out, Wo, ao, rW2, srel2);
  k_cvt<<<(NNODES * 128 / 8 + 255) / 256, 256, 0, stream>>>(x, Xb, NNODES * 128 / 8);
  k_packb<1><<<256, 128, 0, stream>>>(Wh, Wb1);
  k_packb<2><<<256, 128, 0, stream>>>(Wo, Wb2);

  const int GEMM_GRID = (NNODES + 63) / 64;  // 1563

  // --- layer 1 ---
  k_gemm_mfma<1><<<GEMM_GRID, 256, 0, stream>>>(Xb, Wb1, ah, xW, sc1);
  k_agg1<<<NNODES / 4, 256, 0, stream>>>(rowstart, perm, dstA, et, et2, xW, sc1, rW1, srel1,
                                         x1b);

  // --- layer 2 ---
  k_gemm_mfma<2><<<GEMM_GRID, 256, 0, stream>>>(x1b, Wb2, ao, xW, sc2);
  k_agg2<<<NNODES / 4, 256, 0, stream>>>(rowstart, perm, dstA, et, et2, xW, sc2, rW2, srel2,
                                         out);
}

// Round 6
// 462.268 us; speedup vs baseline: 1.7992x; 1.0597x over previous
//
#include <hip/hip_runtime.h>
#include <math.h>

// Problem constants (from reference)
#define NNODES 100000
#define NREL 500
#define E1 288000
#define ETOT 320000
#define LALPHA 0.2f
#define SEPS 1e-16f
#define NB_SCAN ((NNODES + 255) / 256)  // 391 blocks of 256 for the scan

typedef __attribute__((ext_vector_type(8))) short bf16x8;
typedef __attribute__((ext_vector_type(4))) float f32x4;

// fp32 -> bf16 (round-to-nearest-even), header-independent
__device__ __forceinline__ unsigned short f2bf(float x) {
  unsigned int u = __float_as_uint(x);
  unsigned int r = (u + 0x7fffu + ((u >> 16) & 1u)) >> 16;
  return (unsigned short)r;
}
// pack two fp32 as bf16 pair (lo, hi) in one uint
__device__ __forceinline__ unsigned int packbf2(float lo, float hi) {
  return (unsigned int)f2bf(lo) | ((unsigned int)f2bf(hi) << 16);
}
__device__ __forceinline__ float unpk_lo(unsigned int u) { return __uint_as_float(u << 16); }
__device__ __forceinline__ float unpk_hi(unsigned int u) {
  return __uint_as_float(u & 0xffff0000u);
}

// ---------------- wave (64-lane) reductions ----------------
__device__ __forceinline__ float wave_max64(float v) {
#pragma unroll
  for (int o = 32; o >= 1; o >>= 1) v = fmaxf(v, __shfl_xor(v, o, 64));
  return v;
}
__device__ __forceinline__ float wave_sum64(float v) {
#pragma unroll
  for (int o = 32; o >= 1; o >>= 1) v += __shfl_xor(v, o, 64);
  return v;
}

// ---------------- CSR build ----------------
__global__ void k_zero_int(int* __restrict__ p, int n) {
  int i = blockIdx.x * blockDim.x + threadIdx.x;
  if (i < n) p[i] = 0;
}

__global__ void k_count(const int* __restrict__ src, int* __restrict__ cnt) {
  int e = blockIdx.x * blockDim.x + threadIdx.x;
  if (e < ETOT) atomicAdd(&cnt[src[e]], 1);
}

__global__ void k_scan_a(const int* __restrict__ cnt, int* __restrict__ rowstart,
                         int* __restrict__ blockTot) {
  __shared__ int s[256];
  int t = threadIdx.x;
  int idx = blockIdx.x * 256 + t;
  int v = (idx < NNODES) ? cnt[idx] : 0;
  s[t] = v;
  __syncthreads();
  for (int off = 1; off < 256; off <<= 1) {
    int xv = (t >= off) ? s[t - off] : 0;
    __syncthreads();
    s[t] += xv;
    __syncthreads();
  }
  if (idx < NNODES) rowstart[idx] = s[t] - v;  // exclusive within block
  if (t == 255) blockTot[blockIdx.x] = s[255];
}

__global__ void k_scan_b(const int* __restrict__ blockTot, int* __restrict__ blockOff) {
  __shared__ int s[512];
  int t = threadIdx.x;
  int v = (t < NB_SCAN) ? blockTot[t] : 0;
  s[t] = v;
  __syncthreads();
  for (int off = 1; off < 512; off <<= 1) {
    int xv = (t >= off) ? s[t - off] : 0;
    __syncthreads();
    s[t] += xv;
    __syncthreads();
  }
  if (t < NB_SCAN) blockOff[t] = s[t] - v;  // exclusive
}

__global__ void k_scan_c(int* __restrict__ rowstart, const int* __restrict__ blockOff,
                         int* __restrict__ cursor) {
  int idx = blockIdx.x * 256 + threadIdx.x;
  if (idx < NNODES) {
    int v = rowstart[idx] + blockOff[blockIdx.x];
    rowstart[idx] = v;
    cursor[idx] = v;
  }
  if (idx == 0) rowstart[NNODES] = ETOT;
}

__global__ void k_scatter(const int* __restrict__ src, int* __restrict__ cursor,
                          int* __restrict__ perm) {
  int e = blockIdx.x * blockDim.x + threadIdx.x;
  if (e < ETOT) {
    int pos = atomicAdd(&cursor[src[e]], 1);
    perm[pos] = e;
  }
}

// ---------------- relation-level precompute ----------------
// rW1p[t][l] = bf16pair(rW1[t][h0][l], rW1[t][h1][l]); srel1[t][h] = rW1[t][h] . a_heads[h]
__global__ void k_relprep1(const float* __restrict__ r, const float* __restrict__ Wh,
                           const float* __restrict__ ah, unsigned int* __restrict__ rW1p,
                           float* __restrict__ srel1) {
  __shared__ float vals[128];
  int t = blockIdx.x;    // 0..499
  int tid = threadIdx.x; // 0..127: h = tid>>6, kk = tid&63
  int h = tid >> 6, kk = tid & 63;
  const float* wcol = Wh + h * 24576 + 256 * 64 + kk;
  const float* rrow = r + t * 128;
  float acc = 0.f;
#pragma unroll 4
  for (int d = 0; d < 128; ++d) acc = fmaf(rrow[d], wcol[d * 64], acc);
  vals[tid] = acc;
  float p = wave_sum64(acc * ah[h * 64 + kk]);
  if (kk == 0) srel1[t * 2 + h] = p;
  __syncthreads();
  if (tid < 64) rW1p[t * 64 + tid] = packbf2(vals[tid], vals[64 + tid]);
}

// r2[t][c] = sum_d r[t][d] * W_r[d][c]   (also one of the two outputs)
__global__ void k_r2(const float* __restrict__ r, const float* __restrict__ Wr,
                     float* __restrict__ r2out) {
  int t = blockIdx.x;   // 0..499
  int c = threadIdx.x;  // 0..127
  float acc = 0.f;
#pragma unroll 4
  for (int d = 0; d < 128; ++d) acc = fmaf(r[t * 128 + d], Wr[d * 128 + c], acc);
  r2out[t * 128 + c] = acc;
}

// rW2p[t][l] = bf16pair(rW2[t][l], rW2[t][64+l]); srel2[t] = rW2[t] . a_out
__global__ void k_relprep2(const float* __restrict__ r2, const float* __restrict__ Wo,
                           const float* __restrict__ ao, unsigned int* __restrict__ rW2p,
                           float* __restrict__ srel2) {
  __shared__ float s[128];
  __shared__ float vals[128];
  int t = blockIdx.x;   // 0..499
  int k = threadIdx.x;  // 0..127
  float acc = 0.f;
#pragma unroll 4
  for (int d = 0; d < 128; ++d) acc = fmaf(r2[t * 128 + d], Wo[(256 + d) * 128 + k], acc);
  vals[k] = acc;
  s[k] = acc * ao[k];
  __syncthreads();
  for (int off = 64; off >= 1; off >>= 1) {
    if (k < off) s[k] += s[k + off];
    __syncthreads();
  }
  if (k == 0) srel2[t] = s[0];
  if (k < 64) rW2p[t * 64 + k] = packbf2(vals[k], vals[64 + k]);
}

// ---------------- MFMA weight packing: Wb[c][d] bf16, B^T layout ----------------
// LAYER1: c = part*128 + h*64 + kc -> Wh[h][part*128+d][kc]
// LAYER2: c = part*128 + kc       -> Wo[part*128+d][kc]
template <int LAYER>
__global__ void k_packb(const float* __restrict__ W, unsigned short* __restrict__ Wb) {
  int c = blockIdx.x;   // 0..255
  int d = threadIdx.x;  // 0..127
  float v;
  if (LAYER == 1) {
    int h = (c >> 6) & 1, part = c >> 7, kc = c & 63;
    v = W[h * 24576 + (part * 128 + d) * 64 + kc];
  } else {
    int part = c >> 7, kc = c & 127;
    v = W[(part * 128 + d) * 128 + kc];
  }
  Wb[c * 128 + d] = f2bf(v);
}

// ---------------- MFMA GEMM: xWp[N][128] (bf16-pair) = X[N][128] @ Wb^T ----------------
// 4 waves/block, wave handles 16 rows x 256 cols (16 tiles of 16x16, K=128 in 4 steps).
// A frag: row=lane&15, k=(lane>>4)*8+j; B^T symmetric; D: col=lane&15, row=(lane>>4)*4+reg.
// Output packed: xWp[n][j] = pair(col, col+64): j<64 -> part0 (src), j>=64 -> part1 (dst).
// Fused epilogue: sc[n][slot] = sum_c Y[n][c]*avec[c&127].
// LAYER1 A = fp32 x (converted in-register); LAYER2 A = bf16 x1.
template <int LAYER>
__global__ __launch_bounds__(256) void k_gemm_mfma(const void* __restrict__ Xin,
                                                   const unsigned short* __restrict__ Wb,
                                                   const float* __restrict__ avec,
                                                   unsigned int* __restrict__ xWp,
                                                   float* __restrict__ sc) {
  const int lane = threadIdx.x & 63;
  const int wave = threadIdx.x >> 6;
  const int rb = blockIdx.x * 64 + wave * 16;  // wave's first row
  const int colv = lane & 15;
  const int kg = lane >> 4;  // k-group / row-group

  int ar = rb + colv;
  ar = (ar < NNODES) ? ar : (NNODES - 1);
  bf16x8 a[4];
  if (LAYER == 1) {
    const float* xf = (const float*)Xin + (size_t)ar * 128 + kg * 8;
#pragma unroll
    for (int s = 0; s < 4; ++s) {
      float4 f0 = *(const float4*)(xf + s * 32);
      float4 f1 = *(const float4*)(xf + s * 32 + 4);
      union {
        unsigned short us[8];
        bf16x8 v;
      } tmp;
      tmp.us[0] = f2bf(f0.x); tmp.us[1] = f2bf(f0.y);
      tmp.us[2] = f2bf(f0.z); tmp.us[3] = f2bf(f0.w);
      tmp.us[4] = f2bf(f1.x); tmp.us[5] = f2bf(f1.y);
      tmp.us[6] = f2bf(f1.z); tmp.us[7] = f2bf(f1.w);
      a[s] = tmp.v;
    }
  } else {
    const unsigned short* xb = (const unsigned short*)Xin + (size_t)ar * 128 + kg * 8;
#pragma unroll
    for (int s = 0; s < 4; ++s) a[s] = *(const bf16x8*)(xb + s * 32);
  }

  f32x4 acc[16];
#pragma unroll
  for (int t = 0; t < 16; ++t) acc[t] = (f32x4){0.f, 0.f, 0.f, 0.f};

#pragma unroll
  for (int t = 0; t < 16; ++t) {
    const unsigned short* wp = Wb + (size_t)(t * 16 + colv) * 128 + kg * 8;
#pragma unroll
    for (int s = 0; s < 4; ++s) {
      bf16x8 b = *(const bf16x8*)(wp + s * 32);
      acc[t] = __builtin_amdgcn_mfma_f32_16x16x32_bf16(a[s], b, acc[t], 0, 0, 0);
    }
  }

  const int grow = rb + kg * 4;

  // ---- packed bf16-pair store ----
#pragma unroll
  for (int i = 0; i < 4; ++i) {
    if (grow + i < NNODES) {
      unsigned int* orow = xWp + (size_t)(grow + i) * 128;
#pragma unroll
      for (int tt = 0; tt < 4; ++tt)
        orow[tt * 16 + colv] = packbf2(acc[tt][i], acc[tt + 4][i]);
#pragma unroll
      for (int tt = 8; tt < 12; ++tt)
        orow[64 + (tt - 8) * 16 + colv] = packbf2(acc[tt][i], acc[tt + 4][i]);
    }
  }

  // ---- attention-scalar epilogue (fp32 exact) ----
  const int NS = (LAYER == 1) ? 4 : 2;
  float psum[4][4];
#pragma unroll
  for (int i = 0; i < 4; ++i)
#pragma unroll
    for (int s = 0; s < 4; ++s) psum[i][s] = 0.f;

#pragma unroll
  for (int t = 0; t < 16; ++t) {
    int c = t * 16 + colv;
    float av = avec[c & 127];
    int slot = (LAYER == 1) ? (((c >> 6) & 1) * 2 + (c >> 7)) : (c >> 7);
#pragma unroll
    for (int i = 0; i < 4; ++i) psum[i][slot] = fmaf(acc[t][i], av, psum[i][slot]);
  }
#pragma unroll
  for (int i = 0; i < 4; ++i)
#pragma unroll
    for (int s = 0; s < 4; ++s) {
      if (s < NS) {
        float v = psum[i][s];
        v += __shfl_xor(v, 1, 64);
        v += __shfl_xor(v, 2, 64);
        v += __shfl_xor(v, 4, 64);
        v += __shfl_xor(v, 8, 64);
        psum[i][s] = v;
      }
    }
  if (colv == 0) {
#pragma unroll
    for (int i = 0; i < 4; ++i) {
      if (grow + i < NNODES) {
#pragma unroll
        for (int s = 0; s < 4; ++s)
          if (s < NS) sc[(size_t)(grow + i) * NS + s] = psum[i][s];
      }
    }
  }
}

// ---------------- layer-1 aggregation: one wave per node, both heads, online softmax ----
// xWp/rW1p bf16-paired; writes x1 in bf16 (only consumed by GEMM2)
__global__ __launch_bounds__(256) void k_agg1(
    const int* __restrict__ rowstart, const int* __restrict__ perm,
    const int* __restrict__ dstA, const int* __restrict__ et, const int* __restrict__ et2,
    const unsigned int* __restrict__ xWp, const float* __restrict__ sc1,
    const unsigned int* __restrict__ rW1p, const float* __restrict__ srel1,
    unsigned short* __restrict__ x1b) {
  int n = blockIdx.x * 4 + (threadIdx.x >> 6);
  int lane = threadIdx.x & 63;
  int s0 = rowstart[n];
  int deg = rowstart[n + 1] - s0;
  float r0 = 0.f, r1 = 0.f;
  if (deg > 0) {
    float4 scn = ((const float4*)sc1)[n];
    const float ss0 = scn.x, ss1 = scn.z;
    float m0 = -3.4e38f, m1 = -3.4e38f, d0 = 0.f, d1 = 0.f, acc0 = 0.f, acc1 = 0.f;
    for (int base = 0; base < deg; base += 64) {
      int i = base + lane;
      int dn = 0, t1 = 0, t2 = -1;
      float lg0 = -3.4e38f, lg1 = -3.4e38f;
      if (i < deg) {
        int ed = perm[s0 + i];
        dn = dstA[ed];
        float rel0, rel1;
        if (ed < E1) {
          t1 = et[ed];
          float2 sr = ((const float2*)srel1)[t1];
          rel0 = sr.x;
          rel1 = sr.y;
        } else {
          int j = ed - E1;
          t1 = et2[2 * j];
          t2 = et2[2 * j + 1];
          float2 sa = ((const float2*)srel1)[t1];
          float2 sb = ((const float2*)srel1)[t2];
          rel0 = sa.x + sb.x;
          rel1 = sa.y + sb.y;
        }
        float4 scd = ((const float4*)sc1)[dn];
        float e0 = ss0 + scd.y + rel0;
        float e1 = ss1 + scd.w + rel1;
        lg0 = (e0 >= 0.f) ? e0 : LALPHA * e0;
        lg1 = (e1 >= 0.f) ? e1 : LALPHA * e1;
      }
      float nm0 = fmaxf(m0, wave_max64(lg0));
      float nm1 = fmaxf(m1, wave_max64(lg1));
      float rs0 = __expf(m0 - nm0), rs1 = __expf(m1 - nm1);
      float w0 = __expf(lg0 - nm0), w1 = __expf(lg1 - nm1);  // invalid lanes -> 0
      d0 = d0 * rs0 + wave_sum64(w0);
      d1 = d1 * rs1 + wave_sum64(w1);
      acc0 *= rs0;
      acc1 *= rs1;
      m0 = nm0;
      m1 = nm1;
      int cnt = min(64, deg - base);
      for (int e2 = 0; e2 < cnt; ++e2) {
        float a0 = __shfl(w0, e2, 64);
        float a1 = __shfl(w1, e2, 64);
        int dne = __shfl(dn, e2, 64);
        int t1e = __shfl(t1, e2, 64);
        int t2e = __shfl(t2, e2, 64);
        unsigned int ur = rW1p[(size_t)t1e * 64 + lane];
        float rv0 = unpk_lo(ur), rv1 = unpk_hi(ur);
        if (t2e >= 0) {  // wave-uniform branch
          unsigned int uq = rW1p[(size_t)t2e * 64 + lane];
          rv0 += unpk_lo(uq);
          rv1 += unpk_hi(uq);
        }
        unsigned int ud = xWp[(size_t)dne * 128 + 64 + lane];
        acc0 = fmaf(a0, unpk_lo(ud) + rv0, acc0);
        acc1 = fmaf(a1, unpk_hi(ud) + rv1, acc1);
      }
    }
    float inv0 = 1.f / (d0 + SEPS), inv1 = 1.f / (d1 + SEPS);
    unsigned int us = xWp[(size_t)n * 128 + lane];
    float o0 = (acc0 + d0 * unpk_lo(us)) * inv0;
    float o1 = (acc1 + d1 * unpk_hi(us)) * inv1;
    r0 = (o0 > 0.f) ? o0 : __expf(o0) - 1.f;  // elu (concat=True)
    r1 = (o1 > 0.f) ? o1 : __expf(o1) - 1.f;
  }
  x1b[(size_t)n * 128 + lane] = f2bf(r0);
  x1b[(size_t)n * 128 + 64 + lane] = f2bf(r1);
}

// ---------------- layer-2 aggregation: one wave per node, 128 dims, online softmax ----
__global__ __launch_bounds__(256) void k_agg2(
    const int* __restrict__ rowstart, const int* __restrict__ perm,
    const int* __restrict__ dstA, const int* __restrict__ et, const int* __restrict__ et2,
    const unsigned int* __restrict__ xWp, const float* __restrict__ sc2,
    const unsigned int* __restrict__ rW2p, const float* __restrict__ srel2,
    float* __restrict__ outp) {
  int n = blockIdx.x * 4 + (threadIdx.x >> 6);
  int lane = threadIdx.x & 63;
  int s0 = rowstart[n];
  int deg = rowstart[n + 1] - s0;
  float r0 = 0.f, r1 = 0.f;
  if (deg > 0) {
    const float ss = ((const float2*)sc2)[n].x;
    float m = -3.4e38f, d = 0.f, acc0 = 0.f, acc1 = 0.f;
    for (int base = 0; base < deg; base += 64) {
      int i = base + lane;
      int dn = 0, t1 = 0, t2 = -1;
      float lg = -3.4e38f;
      if (i < deg) {
        int ed = perm[s0 + i];
        dn = dstA[ed];
        float rel;
        if (ed < E1) {
          t1 = et[ed];
          rel = srel2[t1];
        } else {
          int j = ed - E1;
          t1 = et2[2 * j];
          t2 = et2[2 * j + 1];
          rel = srel2[t1] + srel2[t2];
        }
        float e = ss + ((const float2*)sc2)[dn].y + rel;
        lg = (e >= 0.f) ? e : LALPHA * e;
      }
      float nm = fmaxf(m, wave_max64(lg));
      float rs = __expf(m - nm);
      float w = __expf(lg - nm);
      d = d * rs + wave_sum64(w);
      acc0 *= rs;
      acc1 *= rs;
      m = nm;
      int cnt = min(64, deg - base);
      for (int e2 = 0; e2 < cnt; ++e2) {
        float a = __shfl(w, e2, 64);
        int dne = __shfl(dn, e2, 64);
        int t1e = __shfl(t1, e2, 64);
        int t2e = __shfl(t2, e2, 64);
        unsigned int ur = rW2p[(size_t)t1e * 64 + lane];
        float rv0 = unpk_lo(ur), rv1 = unpk_hi(ur);
        if (t2e >= 0) {
          unsigned int uq = rW2p[(size_t)t2e * 64 + lane];
          rv0 += unpk_lo(uq);
          rv1 += unpk_hi(uq);
        }
        unsigned int ud = xWp[(size_t)dne * 128 + 64 + lane];
        acc0 = fmaf(a, unpk_lo(ud) + rv0, acc0);
        acc1 = fmaf(a, unpk_hi(ud) + rv1, acc1);
      }
    }
    float inv = 1.f / (d + SEPS);
    unsigned int us = xWp[(size_t)n * 128 + lane];
    float o0 = (acc0 + d * unpk_lo(us)) * inv;
    float o1 = (acc1 + d * unpk_hi(us)) * inv;
    r0 = (o0 > 0.f) ? o0 : __expf(o0) - 1.f;  // final elu
    r1 = (o1 > 0.f) ? o1 : __expf(o1) - 1.f;
  }
  outp[(size_t)n * 128 + lane] = r0;
  outp[(size_t)n * 128 + 64 + lane] = r1;
}

// ---------------- launch ----------------
extern "C" void kernel_launch(void* const* d_in, const int* in_sizes, int n_in, void* d_out,
                              int out_size, void* d_ws, size_t ws_size, hipStream_t stream) {
  const int* edge_index = (const int*)d_in[0];
  const int* srcA = edge_index;
  const int* dstA = edge_index + ETOT;
  const float* x = (const float*)d_in[1];
  const float* r = (const float*)d_in[2];
  const int* et = (const int*)d_in[3];
  const int* et2 = (const int*)d_in[4];
  const float* Wh = (const float*)d_in[5];
  const float* ah = (const float*)d_in[6];
  const float* Wo = (const float*)d_in[7];
  const float* ao = (const float*)d_in[8];
  const float* Wr = (const float*)d_in[9];
  float* out = (float*)d_out;
  float* r2out = out + (size_t)NNODES * 128;

  // workspace layout (256-B aligned chunks)
  char* ws = (char*)d_ws;
  size_t o = 0;
  auto alloc = [&](size_t bytes) {
    char* p = ws + o;
    o += (bytes + 255) & ~(size_t)255;
    return p;
  };
  unsigned int* xWp = (unsigned int*)alloc((size_t)NNODES * 128 * 4);  // bf16-pair xW
  float* sc1 = (float*)alloc((size_t)NNODES * 4 * 4);
  float* sc2 = (float*)alloc((size_t)NNODES * 2 * 4);
  unsigned int* rW1p = (unsigned int*)alloc((size_t)NREL * 64 * 4);
  float* srel1 = (float*)alloc(2 * NREL * 4);
  unsigned int* rW2p = (unsigned int*)alloc((size_t)NREL * 64 * 4);
  float* srel2 = (float*)alloc(NREL * 4);
  unsigned short* x1b = (unsigned short*)alloc((size_t)NNODES * 128 * 2);  // bf16 x1
  unsigned short* Wb1 = (unsigned short*)alloc(256 * 128 * 2);
  unsigned short* Wb2 = (unsigned short*)alloc(256 * 128 * 2);
  int* cnt = (int*)alloc(NNODES * 4);
  int* rowstart = (int*)alloc((NNODES + 1) * 4);
  int* cursor = (int*)alloc(NNODES * 4);
  int* blockTot = (int*)alloc(512 * 4);
  int* blockOff = (int*)alloc(512 * 4);
  int* perm = (int*)alloc(ETOT * 4);

  // --- CSR build ---
  k_zero_int<<<(NNODES + 255) / 256, 256, 0, stream>>>(cnt, NNODES);
  k_count<<<(ETOT + 255) / 256, 256, 0, stream>>>(srcA, cnt);
  k_scan_a<<<NB_SCAN, 256, 0, stream>>>(cnt, rowstart, blockTot);
  k_scan_b<<<1, 512, 0, stream>>>(blockTot, blockOff);
  k_scan_c<<<NB_SCAN, 256, 0, stream>>>(rowstart, blockOff, cursor);
  k_scatter<<<(ETOT + 255) / 256, 256, 0, stream>>>(srcA, cursor, perm);

  // --- relation precompute + weight staging ---
  k_relprep1<<<NREL, 128, 0, stream>>>(r, Wh, ah, rW1p, srel1);
  k_r2<<<NREL, 128, 0, stream>>>(r, Wr, r2out);
  k_relprep2<<<NREL, 128, 0, stream>>>(r2out, Wo, ao, rW2p, srel2);
  k_packb<1><<<256, 128, 0, stream>>>(Wh, Wb1);
  k_packb<2><<<256, 128, 0, stream>>>(Wo, Wb2);

  const int GEMM_GRID = (NNODES + 63) / 64;  // 1563

  // --- layer 1 ---
  k_gemm_mfma<1><<<GEMM_GRID, 256, 0, stream>>>(x, Wb1, ah, xWp, sc1);
  k_agg1<<<NNODES / 4, 256, 0, stream>>>(rowstart, perm, dstA, et, et2, xWp, sc1, rW1p, srel1,
                                         x1b);

  // --- layer 2 ---
  k_gemm_mfma<2><<<GEMM_GRID, 256, 0, stream>>>(x1b, Wb2, ao, xWp, sc2);
  k_agg2<<<NNODES / 4, 256, 0, stream>>>(rowstart, perm, dstA, et, et2, xWp, sc2, rW2p, srel2,
                                         out);
}

// Round 7
// 452.679 us; speedup vs baseline: 1.8373x; 1.0212x over previous
//
#include <hip/hip_runtime.h>
#include <math.h>

// Problem constants (from reference)
#define NNODES 100000
#define NREL 500
#define E1 288000
#define ETOT 320000
#define LALPHA 0.2f
#define SEPS 1e-16f
#define NB_SCAN ((NNODES + 255) / 256)  // 391 blocks of 256 for the scan

typedef __attribute__((ext_vector_type(8))) short bf16x8;
typedef __attribute__((ext_vector_type(4))) float f32x4;

// fp32 -> bf16 (round-to-nearest-even), header-independent
__device__ __forceinline__ unsigned short f2bf(float x) {
  unsigned int u = __float_as_uint(x);
  unsigned int r = (u + 0x7fffu + ((u >> 16) & 1u)) >> 16;
  return (unsigned short)r;
}
// pack two fp32 as bf16 pair (lo, hi) in one uint
__device__ __forceinline__ unsigned int packbf2(float lo, float hi) {
  return (unsigned int)f2bf(lo) | ((unsigned int)f2bf(hi) << 16);
}
__device__ __forceinline__ float unpk_lo(unsigned int u) { return __uint_as_float(u << 16); }
__device__ __forceinline__ float unpk_hi(unsigned int u) {
  return __uint_as_float(u & 0xffff0000u);
}
__device__ __forceinline__ float lrelu(float e) { return (e >= 0.f) ? e : LALPHA * e; }

// ---------------- wave (64-lane) reductions ----------------
__device__ __forceinline__ float wave_max64(float v) {
#pragma unroll
  for (int o = 32; o >= 1; o >>= 1) v = fmaxf(v, __shfl_xor(v, o, 64));
  return v;
}
__device__ __forceinline__ float wave_sum64(float v) {
#pragma unroll
  for (int o = 32; o >= 1; o >>= 1) v += __shfl_xor(v, o, 64);
  return v;
}

// ---------------- CSR build ----------------
__global__ void k_zero_int(int* __restrict__ p, int n) {
  int i = blockIdx.x * blockDim.x + threadIdx.x;
  if (i < n) p[i] = 0;
}

__global__ void k_count(const int* __restrict__ src, int* __restrict__ cnt) {
  int e = blockIdx.x * blockDim.x + threadIdx.x;
  if (e < ETOT) atomicAdd(&cnt[src[e]], 1);
}

__global__ void k_scan_a(const int* __restrict__ cnt, int* __restrict__ rowstart,
                         int* __restrict__ blockTot) {
  __shared__ int s[256];
  int t = threadIdx.x;
  int idx = blockIdx.x * 256 + t;
  int v = (idx < NNODES) ? cnt[idx] : 0;
  s[t] = v;
  __syncthreads();
  for (int off = 1; off < 256; off <<= 1) {
    int xv = (t >= off) ? s[t - off] : 0;
    __syncthreads();
    s[t] += xv;
    __syncthreads();
  }
  if (idx < NNODES) rowstart[idx] = s[t] - v;  // exclusive within block
  if (t == 255) blockTot[blockIdx.x] = s[255];
}

__global__ void k_scan_b(const int* __restrict__ blockTot, int* __restrict__ blockOff) {
  __shared__ int s[512];
  int t = threadIdx.x;
  int v = (t < NB_SCAN) ? blockTot[t] : 0;
  s[t] = v;
  __syncthreads();
  for (int off = 1; off < 512; off <<= 1) {
    int xv = (t >= off) ? s[t - off] : 0;
    __syncthreads();
    s[t] += xv;
    __syncthreads();
  }
  if (t < NB_SCAN) blockOff[t] = s[t] - v;  // exclusive
}

__global__ void k_scan_c(int* __restrict__ rowstart, const int* __restrict__ blockOff,
                         int* __restrict__ cursor) {
  int idx = blockIdx.x * 256 + threadIdx.x;
  if (idx < NNODES) {
    int v = rowstart[idx] + blockOff[blockIdx.x];
    rowstart[idx] = v;
    cursor[idx] = v;
  }
  if (idx == 0) rowstart[NNODES] = ETOT;
}

__global__ void k_scatter(const int* __restrict__ src, int* __restrict__ cursor,
                          int* __restrict__ perm) {
  int e = blockIdx.x * blockDim.x + threadIdx.x;
  if (e < ETOT) {
    int pos = atomicAdd(&cursor[src[e]], 1);
    perm[pos] = e;
  }
}

// ---------------- relation-level precompute ----------------
// rW1p[t][l] = bf16pair(rW1[t][h0][l], rW1[t][h1][l]); srel1[t][h] = rW1[t][h] . a_heads[h]
__global__ void k_relprep1(const float* __restrict__ r, const float* __restrict__ Wh,
                           const float* __restrict__ ah, unsigned int* __restrict__ rW1p,
                           float* __restrict__ srel1) {
  __shared__ float vals[128];
  int t = blockIdx.x;    // 0..499
  int tid = threadIdx.x; // 0..127: h = tid>>6, kk = tid&63
  int h = tid >> 6, kk = tid & 63;
  const float* wcol = Wh + h * 24576 + 256 * 64 + kk;
  const float* rrow = r + t * 128;
  float acc = 0.f;
#pragma unroll 4
  for (int d = 0; d < 128; ++d) acc = fmaf(rrow[d], wcol[d * 64], acc);
  vals[tid] = acc;
  float p = wave_sum64(acc * ah[h * 64 + kk]);
  if (kk == 0) srel1[t * 2 + h] = p;
  __syncthreads();
  if (tid < 64) rW1p[t * 64 + tid] = packbf2(vals[tid], vals[64 + tid]);
}

// r2[t][c] = sum_d r[t][d] * W_r[d][c]   (also one of the two outputs)
__global__ void k_r2(const float* __restrict__ r, const float* __restrict__ Wr,
                     float* __restrict__ r2out) {
  int t = blockIdx.x;   // 0..499
  int c = threadIdx.x;  // 0..127
  float acc = 0.f;
#pragma unroll 4
  for (int d = 0; d < 128; ++d) acc = fmaf(r[t * 128 + d], Wr[d * 128 + c], acc);
  r2out[t * 128 + c] = acc;
}

// rW2p[t][l] = bf16pair(rW2[t][l], rW2[t][64+l]); srel2[t] = rW2[t] . a_out
__global__ void k_relprep2(const float* __restrict__ r2, const float* __restrict__ Wo,
                           const float* __restrict__ ao, unsigned int* __restrict__ rW2p,
                           float* __restrict__ srel2) {
  __shared__ float s[128];
  __shared__ float vals[128];
  int t = blockIdx.x;   // 0..499
  int k = threadIdx.x;  // 0..127
  float acc = 0.f;
#pragma unroll 4
  for (int d = 0; d < 128; ++d) acc = fmaf(r2[t * 128 + d], Wo[(256 + d) * 128 + k], acc);
  vals[k] = acc;
  s[k] = acc * ao[k];
  __syncthreads();
  for (int off = 64; off >= 1; off >>= 1) {
    if (k < off) s[k] += s[k + off];
    __syncthreads();
  }
  if (k == 0) srel2[t] = s[0];
  if (k < 64) rW2p[t * 64 + k] = packbf2(vals[k], vals[64 + k]);
}

// ---------------- MFMA weight packing: Wb[c][d] bf16, B^T layout ----------------
template <int LAYER>
__global__ void k_packb(const float* __restrict__ W, unsigned short* __restrict__ Wb) {
  int c = blockIdx.x;   // 0..255
  int d = threadIdx.x;  // 0..127
  float v;
  if (LAYER == 1) {
    int h = (c >> 6) & 1, part = c >> 7, kc = c & 63;
    v = W[h * 24576 + (part * 128 + d) * 64 + kc];
  } else {
    int part = c >> 7, kc = c & 127;
    v = W[(part * 128 + d) * 128 + kc];
  }
  Wb[c * 128 + d] = f2bf(v);
}

// ---------------- MFMA GEMM: xWp[N][128] (bf16-pair) = X[N][128] @ Wb^T ----------------
template <int LAYER>
__global__ __launch_bounds__(256) void k_gemm_mfma(const void* __restrict__ Xin,
                                                   const unsigned short* __restrict__ Wb,
                                                   const float* __restrict__ avec,
                                                   unsigned int* __restrict__ xWp,
                                                   float* __restrict__ sc) {
  const int lane = threadIdx.x & 63;
  const int wave = threadIdx.x >> 6;
  const int rb = blockIdx.x * 64 + wave * 16;  // wave's first row
  const int colv = lane & 15;
  const int kg = lane >> 4;  // k-group / row-group

  int ar = rb + colv;
  ar = (ar < NNODES) ? ar : (NNODES - 1);
  bf16x8 a[4];
  if (LAYER == 1) {
    const float* xf = (const float*)Xin + (size_t)ar * 128 + kg * 8;
#pragma unroll
    for (int s = 0; s < 4; ++s) {
      float4 f0 = *(const float4*)(xf + s * 32);
      float4 f1 = *(const float4*)(xf + s * 32 + 4);
      union {
        unsigned short us[8];
        bf16x8 v;
      } tmp;
      tmp.us[0] = f2bf(f0.x); tmp.us[1] = f2bf(f0.y);
      tmp.us[2] = f2bf(f0.z); tmp.us[3] = f2bf(f0.w);
      tmp.us[4] = f2bf(f1.x); tmp.us[5] = f2bf(f1.y);
      tmp.us[6] = f2bf(f1.z); tmp.us[7] = f2bf(f1.w);
      a[s] = tmp.v;
    }
  } else {
    const unsigned short* xb = (const unsigned short*)Xin + (size_t)ar * 128 + kg * 8;
#pragma unroll
    for (int s = 0; s < 4; ++s) a[s] = *(const bf16x8*)(xb + s * 32);
  }

  f32x4 acc[16];
#pragma unroll
  for (int t = 0; t < 16; ++t) acc[t] = (f32x4){0.f, 0.f, 0.f, 0.f};

#pragma unroll
  for (int t = 0; t < 16; ++t) {
    const unsigned short* wp = Wb + (size_t)(t * 16 + colv) * 128 + kg * 8;
#pragma unroll
    for (int s = 0; s < 4; ++s) {
      bf16x8 b = *(const bf16x8*)(wp + s * 32);
      acc[t] = __builtin_amdgcn_mfma_f32_16x16x32_bf16(a[s], b, acc[t], 0, 0, 0);
    }
  }

  const int grow = rb + kg * 4;

  // ---- packed bf16-pair store ----
#pragma unroll
  for (int i = 0; i < 4; ++i) {
    if (grow + i < NNODES) {
      unsigned int* orow = xWp + (size_t)(grow + i) * 128;
#pragma unroll
      for (int tt = 0; tt < 4; ++tt)
        orow[tt * 16 + colv] = packbf2(acc[tt][i], acc[tt + 4][i]);
#pragma unroll
      for (int tt = 8; tt < 12; ++tt)
        orow[64 + (tt - 8) * 16 + colv] = packbf2(acc[tt][i], acc[tt + 4][i]);
    }
  }

  // ---- attention-scalar epilogue (fp32 exact) ----
  const int NS = (LAYER == 1) ? 4 : 2;
  float psum[4][4];
#pragma unroll
  for (int i = 0; i < 4; ++i)
#pragma unroll
    for (int s = 0; s < 4; ++s) psum[i][s] = 0.f;

#pragma unroll
  for (int t = 0; t < 16; ++t) {
    int c = t * 16 + colv;
    float av = avec[c & 127];
    int slot = (LAYER == 1) ? (((c >> 6) & 1) * 2 + (c >> 7)) : (c >> 7);
#pragma unroll
    for (int i = 0; i < 4; ++i) psum[i][slot] = fmaf(acc[t][i], av, psum[i][slot]);
  }
#pragma unroll
  for (int i = 0; i < 4; ++i)
#pragma unroll
    for (int s = 0; s < 4; ++s) {
      if (s < NS) {
        float v = psum[i][s];
        v += __shfl_xor(v, 1, 64);
        v += __shfl_xor(v, 2, 64);
        v += __shfl_xor(v, 4, 64);
        v += __shfl_xor(v, 8, 64);
        psum[i][s] = v;
      }
    }
  if (colv == 0) {
#pragma unroll
    for (int i = 0; i < 4; ++i) {
      if (grow + i < NNODES) {
#pragma unroll
        for (int s = 0; s < 4; ++s)
          if (s < NS) sc[(size_t)(grow + i) * NS + s] = psum[i][s];
      }
    }
  }
}

// ---------------- edge-parallel logit precompute ----------------
// Layer 1: lgp1[p] = (leaky logit h0, h1) for sorted edge p; also srcp/dnp/t12 (graph, reused).
__global__ void k_eprep1(const int* __restrict__ perm, const int* __restrict__ srcA,
                         const int* __restrict__ dstA, const int* __restrict__ et,
                         const int* __restrict__ et2, const float* __restrict__ sc1,
                         const float* __restrict__ srel1, int* __restrict__ srcp,
                         int* __restrict__ dnp, int2* __restrict__ t12,
                         float2* __restrict__ lgp1) {
  int p = blockIdx.x * 256 + threadIdx.x;
  if (p >= ETOT) return;
  int ed = perm[p];
  int src = srcA[ed], dn = dstA[ed];
  int t1, t2 = -1;
  float rel0, rel1;
  if (ed < E1) {
    t1 = et[ed];
    float2 sr = ((const float2*)srel1)[t1];
    rel0 = sr.x;
    rel1 = sr.y;
  } else {
    int2 tt = ((const int2*)et2)[ed - E1];
    t1 = tt.x;
    t2 = tt.y;
    float2 sa = ((const float2*)srel1)[t1];
    float2 sb = ((const float2*)srel1)[t2];
    rel0 = sa.x + sb.x;
    rel1 = sa.y + sb.y;
  }
  float4 ssv = ((const float4*)sc1)[src];
  float4 sdv = ((const float4*)sc1)[dn];
  lgp1[p] = make_float2(lrelu(ssv.x + sdv.y + rel0), lrelu(ssv.z + sdv.w + rel1));
  srcp[p] = src;
  dnp[p] = dn;
  t12[p] = make_int2(t1, t2);
}

// Layer 2: reuses srcp/dnp/t12.
__global__ void k_eprep2(const int* __restrict__ srcp, const int* __restrict__ dnp,
                         const int2* __restrict__ t12, const float* __restrict__ sc2,
                         const float* __restrict__ srel2, float* __restrict__ lgp2) {
  int p = blockIdx.x * 256 + threadIdx.x;
  if (p >= ETOT) return;
  int src = srcp[p], dn = dnp[p];
  int2 tt = t12[p];
  float rel = srel2[tt.x];
  if (tt.y >= 0) rel += srel2[tt.y];
  float2 ssv = ((const float2*)sc2)[src];
  float2 sdv = ((const float2*)sc2)[dn];
  lgp2[p] = lrelu(ssv.x + sdv.y + rel);
}

// ---------------- layer-1 aggregation: wave/node, 4-edge-parallel groups ----------------
// lane = q + 16*g: group g handles edge s*4+g, lane covers uints jj=q+16k, k=0..3.
__global__ __launch_bounds__(256) void k_agg1(
    const int* __restrict__ rowstart, const float2* __restrict__ lgp1,
    const int* __restrict__ dnp, const int2* __restrict__ t12,
    const unsigned int* __restrict__ xWp, const unsigned int* __restrict__ rW1p,
    unsigned short* __restrict__ x1b) {
  int n = blockIdx.x * 4 + (threadIdx.x >> 6);
  int lane = threadIdx.x & 63;
  int q = lane & 15, g = lane >> 4;
  int s0 = rowstart[n];
  int deg = rowstart[n + 1] - s0;
  int jj = q + 16 * g;
  float r0 = 0.f, r1 = 0.f;
  if (deg > 0) {
    float m0 = -3.4e38f, m1 = -3.4e38f, d0 = 0.f, d1 = 0.f;
    float ac0[4] = {0.f, 0.f, 0.f, 0.f}, ac1[4] = {0.f, 0.f, 0.f, 0.f};
    for (int base = 0; base < deg; base += 64) {
      int i = base + lane;
      float lg0 = -3.4e38f, lg1 = -3.4e38f;
      int dn = 0;
      int2 tt = make_int2(0, -1);
      if (i < deg) {
        float2 l2 = lgp1[s0 + i];
        lg0 = l2.x;
        lg1 = l2.y;
        dn = dnp[s0 + i];
        tt = t12[s0 + i];
      }
      float nm0 = fmaxf(m0, wave_max64(lg0));
      float nm1 = fmaxf(m1, wave_max64(lg1));
      float rs0 = __expf(m0 - nm0), rs1 = __expf(m1 - nm1);
      float w0 = __expf(lg0 - nm0), w1 = __expf(lg1 - nm1);  // invalid lanes -> 0
      d0 = d0 * rs0 + wave_sum64(w0);
      d1 = d1 * rs1 + wave_sum64(w1);
#pragma unroll
      for (int k = 0; k < 4; ++k) {
        ac0[k] *= rs0;
        ac1[k] *= rs1;
      }
      m0 = nm0;
      m1 = nm1;
      int cnt = min(64, deg - base);
      int steps = (cnt + 3) >> 2;
      for (int s = 0; s < steps; ++s) {
        int e = s * 4 + g;  // this group's edge within the chunk (<=63)
        float a0 = __shfl(w0, e, 64);   // e >= cnt -> w from inactive lane = 0
        float a1 = __shfl(w1, e, 64);
        int dne = __shfl(dn, e, 64);
        int t1e = __shfl(tt.x, e, 64);
        int t2e = __shfl(tt.y, e, 64);
        const unsigned int* xr = xWp + (size_t)dne * 128 + 64;
        const unsigned int* rp = rW1p + (size_t)t1e * 64;
#pragma unroll
        for (int k = 0; k < 4; ++k) {
          int j2 = q + 16 * k;
          unsigned int ud = xr[j2];
          unsigned int ur = rp[j2];
          float rv0 = unpk_lo(ur), rv1 = unpk_hi(ur);
          if (t2e >= 0) {  // group-uniform branch
            unsigned int u2 = rW1p[(size_t)t2e * 64 + j2];
            rv0 += unpk_lo(u2);
            rv1 += unpk_hi(u2);
          }
          ac0[k] = fmaf(a0, unpk_lo(ud) + rv0, ac0[k]);
          ac1[k] = fmaf(a1, unpk_hi(ud) + rv1, ac1[k]);
        }
      }
    }
    // reduce across the 4 groups (lanes q, q+16, q+32, q+48)
#pragma unroll
    for (int k = 0; k < 4; ++k) {
      ac0[k] += __shfl_xor(ac0[k], 16, 64);
      ac0[k] += __shfl_xor(ac0[k], 32, 64);
      ac1[k] += __shfl_xor(ac1[k], 16, 64);
      ac1[k] += __shfl_xor(ac1[k], 32, 64);
    }
    // static-index select of this lane's k = g slot (avoid scratch)
    float a0g = (g == 0) ? ac0[0] : (g == 1) ? ac0[1] : (g == 2) ? ac0[2] : ac0[3];
    float a1g = (g == 0) ? ac1[0] : (g == 1) ? ac1[1] : (g == 2) ? ac1[2] : ac1[3];
    float inv0 = 1.f / (d0 + SEPS), inv1 = 1.f / (d1 + SEPS);
    unsigned int us = xWp[(size_t)n * 128 + jj];
    float o0 = (a0g + d0 * unpk_lo(us)) * inv0;
    float o1 = (a1g + d1 * unpk_hi(us)) * inv1;
    r0 = (o0 > 0.f) ? o0 : __expf(o0) - 1.f;  // elu (concat=True)
    r1 = (o1 > 0.f) ? o1 : __expf(o1) - 1.f;
  }
  x1b[(size_t)n * 128 + jj] = f2bf(r0);
  x1b[(size_t)n * 128 + 64 + jj] = f2bf(r1);
}

// ---------------- layer-2 aggregation: same structure, fp32 out ----------------
__global__ __launch_bounds__(256) void k_agg2(
    const int* __restrict__ rowstart, const float* __restrict__ lgp2,
    const int* __restrict__ dnp, const int2* __restrict__ t12,
    const unsigned int* __restrict__ xWp, const unsigned int* __restrict__ rW2p,
    float* __restrict__ outp) {
  int n = blockIdx.x * 4 + (threadIdx.x >> 6);
  int lane = threadIdx.x & 63;
  int q = lane & 15, g = lane >> 4;
  int s0 = rowstart[n];
  int deg = rowstart[n + 1] - s0;
  int jj = q + 16 * g;
  float r0 = 0.f, r1 = 0.f;
  if (deg > 0) {
    float m = -3.4e38f, d = 0.f;
    float ac0[4] = {0.f, 0.f, 0.f, 0.f}, ac1[4] = {0.f, 0.f, 0.f, 0.f};
    for (int base = 0; base < deg; base += 64) {
      int i = base + lane;
      float lg = -3.4e38f;
      int dn = 0;
      int2 tt = make_int2(0, -1);
      if (i < deg) {
        lg = lgp2[s0 + i];
        dn = dnp[s0 + i];
        tt = t12[s0 + i];
      }
      float nm = fmaxf(m, wave_max64(lg));
      float rs = __expf(m - nm);
      float w = __expf(lg - nm);
      d = d * rs + wave_sum64(w);
#pragma unroll
      for (int k = 0; k < 4; ++k) {
        ac0[k] *= rs;
        ac1[k] *= rs;
      }
      m = nm;
      int cnt = min(64, deg - base);
      int steps = (cnt + 3) >> 2;
      for (int s = 0; s < steps; ++s) {
        int e = s * 4 + g;
        float a = __shfl(w, e, 64);
        int dne = __shfl(dn, e, 64);
        int t1e = __shfl(tt.x, e, 64);
        int t2e = __shfl(tt.y, e, 64);
        const unsigned int* xr = xWp + (size_t)dne * 128 + 64;
        const unsigned int* rp = rW2p + (size_t)t1e * 64;
#pragma unroll
        for (int k = 0; k < 4; ++k) {
          int j2 = q + 16 * k;
          unsigned int ud = xr[j2];
          unsigned int ur = rp[j2];
          float rv0 = unpk_lo(ur), rv1 = unpk_hi(ur);
          if (t2e >= 0) {
            unsigned int u2 = rW2p[(size_t)t2e * 64 + j2];
            rv0 += unpk_lo(u2);
            rv1 += unpk_hi(u2);
          }
          ac0[k] = fmaf(a, unpk_lo(ud) + rv0, ac0[k]);
          ac1[k] = fmaf(a, unpk_hi(ud) + rv1, ac1[k]);
        }
      }
    }
#pragma unroll
    for (int k = 0; k < 4; ++k) {
      ac0[k] += __shfl_xor(ac0[k], 16, 64);
      ac0[k] += __shfl_xor(ac0[k], 32, 64);
      ac1[k] += __shfl_xor(ac1[k], 16, 64);
      ac1[k] += __shfl_xor(ac1[k], 32, 64);
    }
    float a0g = (g == 0) ? ac0[0] : (g == 1) ? ac0[1] : (g == 2) ? ac0[2] : ac0[3];
    float a1g = (g == 0) ? ac1[0] : (g == 1) ? ac1[1] : (g == 2) ? ac1[2] : ac1[3];
    float inv = 1.f / (d + SEPS);
    unsigned int us = xWp[(size_t)n * 128 + jj];
    float o0 = (a0g + d * unpk_lo(us)) * inv;
    float o1 = (a1g + d * unpk_hi(us)) * inv;
    r0 = (o0 > 0.f) ? o0 : __expf(o0) - 1.f;  // final elu
    r1 = (o1 > 0.f) ? o1 : __expf(o1) - 1.f;
  }
  outp[(size_t)n * 128 + jj] = r0;
  outp[(size_t)n * 128 + 64 + jj] = r1;
}

// ---------------- launch ----------------
extern "C" void kernel_launch(void* const* d_in, const int* in_sizes, int n_in, void* d_out,
                              int out_size, void* d_ws, size_t ws_size, hipStream_t stream) {
  const int* edge_index = (const int*)d_in[0];
  const int* srcA = edge_index;
  const int* dstA = edge_index + ETOT;
  const float* x = (const float*)d_in[1];
  const float* r = (const float*)d_in[2];
  const int* et = (const int*)d_in[3];
  const int* et2 = (const int*)d_in[4];
  const float* Wh = (const float*)d_in[5];
  const float* ah = (const float*)d_in[6];
  const float* Wo = (const float*)d_in[7];
  const float* ao = (const float*)d_in[8];
  const float* Wr = (const float*)d_in[9];
  float* out = (float*)d_out;
  float* r2out = out + (size_t)NNODES * 128;

  // workspace layout (256-B aligned chunks)
  char* ws = (char*)d_ws;
  size_t o = 0;
  auto alloc = [&](size_t bytes) {
    char* p = ws + o;
    o += (bytes + 255) & ~(size_t)255;
    return p;
  };
  unsigned int* xWp = (unsigned int*)alloc((size_t)NNODES * 128 * 4);  // bf16-pair xW
  float* sc1 = (float*)alloc((size_t)NNODES * 4 * 4);
  float* sc2 = (float*)alloc((size_t)NNODES * 2 * 4);
  unsigned int* rW1p = (unsigned int*)alloc((size_t)NREL * 64 * 4);
  float* srel1 = (float*)alloc(2 * NREL * 4);
  unsigned int* rW2p = (unsigned int*)alloc((size_t)NREL * 64 * 4);
  float* srel2 = (float*)alloc(NREL * 4);
  unsigned short* x1b = (unsigned short*)alloc((size_t)NNODES * 128 * 2);  // bf16 x1
  unsigned short* Wb1 = (unsigned short*)alloc(256 * 128 * 2);
  unsigned short* Wb2 = (unsigned short*)alloc(256 * 128 * 2);
  int* cnt = (int*)alloc(NNODES * 4);
  int* rowstart = (int*)alloc((NNODES + 1) * 4);
  int* cursor = (int*)alloc(NNODES * 4);
  int* blockTot = (int*)alloc(512 * 4);
  int* blockOff = (int*)alloc(512 * 4);
  int* perm = (int*)alloc(ETOT * 4);
  int* srcp = (int*)alloc(ETOT * 4);
  int* dnp = (int*)alloc(ETOT * 4);
  int2* t12 = (int2*)alloc((size_t)ETOT * 8);
  float2* lgp1 = (float2*)alloc((size_t)ETOT * 8);
  float* lgp2 = (float*)alloc(ETOT * 4);

  const int EB = (ETOT + 255) / 256;  // 1250

  // --- CSR build ---
  k_zero_int<<<(NNODES + 255) / 256, 256, 0, stream>>>(cnt, NNODES);
  k_count<<<EB, 256, 0, stream>>>(srcA, cnt);
  k_scan_a<<<NB_SCAN, 256, 0, stream>>>(cnt, rowstart, blockTot);
  k_scan_b<<<1, 512, 0, stream>>>(blockTot, blockOff);
  k_scan_c<<<NB_SCAN, 256, 0, stream>>>(rowstart, blockOff, cursor);
  k_scatter<<<EB, 256, 0, stream>>>(srcA, cursor, perm);

  // --- relation precompute + weight staging ---
  k_relprep1<<<NREL, 128, 0, stream>>>(r, Wh, ah, rW1p, srel1);
  k_r2<<<NREL, 128, 0, stream>>>(r, Wr, r2out);
  k_relprep2<<<NREL, 128, 0, stream>>>(r2out, Wo, ao, rW2p, srel2);
  k_packb<1><<<256, 128, 0, stream>>>(Wh, Wb1);
  k_packb<2><<<256, 128, 0, stream>>>(Wo, Wb2);

  const int GEMM_GRID = (NNODES + 63) / 64;  // 1563

  // --- layer 1 ---
  k_gemm_mfma<1><<<GEMM_GRID, 256, 0, stream>>>(x, Wb1, ah, xWp, sc1);
  k_eprep1<<<EB, 256, 0, stream>>>(perm, srcA, dstA, et, et2, sc1, srel1, srcp, dnp, t12,
                                   lgp1);
  k_agg1<<<NNODES / 4, 256, 0, stream>>>(rowstart, lgp1, dnp, t12, xWp, rW1p, x1b);

  // --- layer 2 ---
  k_gemm_mfma<2><<<GEMM_GRID, 256, 0, stream>>>(x1b, Wb2, ao, xWp, sc2);
  k_eprep2<<<EB, 256, 0, stream>>>(srcp, dnp, t12, sc2, srel2, lgp2);
  k_agg2<<<NNODES / 4, 256, 0, stream>>>(rowstart, lgp2, dnp, t12, xWp, rW2p, out);
}